// Round 4
// baseline (425.115 us; speedup 1.0000x reference)
//
#include <hip/hip_runtime.h>
#include <hip/hip_bf16.h>
#include <math.h>

typedef unsigned short u16;
typedef short s16x8 __attribute__((ext_vector_type(8)));
typedef short s16x4 __attribute__((ext_vector_type(4)));
typedef __bf16 bf16x8v __attribute__((ext_vector_type(8)));
typedef __bf16 bf16x4v __attribute__((ext_vector_type(4)));
typedef float f32x4 __attribute__((ext_vector_type(4)));
typedef unsigned short u16x4 __attribute__((ext_vector_type(4)));

struct Ptr4 { float* p[4]; };
struct TW6 {
    const float* w[6]; u16* o[6]; int mode[6];
    const float *bq, *bk, *bv; float* bqkv;
};

// ---------- conversions ----------
__device__ __forceinline__ u16 f2b(float f) {
    __hip_bfloat16 h = __float2bfloat16(f);
    return __builtin_bit_cast(u16, h);
}

// ---------- raw v_exp_f32 (2^x) with portable fallback ----------
__device__ __forceinline__ float exp2_fast(float x) {
#if __has_builtin(__builtin_amdgcn_exp2f)
    return __builtin_amdgcn_exp2f(x);
#else
    return exp2f(x);
#endif
}

// ---------- MFMA wrappers ----------
__device__ __forceinline__ f32x4 mfma16(s16x8 a, s16x8 b, f32x4 c) {
    return __builtin_amdgcn_mfma_f32_16x16x32_bf16(
        __builtin_bit_cast(bf16x8v, a), __builtin_bit_cast(bf16x8v, b), c, 0, 0, 0);
}

// 16x16x16 bf16 (K=16) — operands 4 bf16/lane (2 VGPR).
__device__ __forceinline__ f32x4 mfma16k16(s16x4 a, s16x4 b, f32x4 c) {
#if __has_builtin(__builtin_amdgcn_mfma_f32_16x16x16bf16_1k)
    return __builtin_amdgcn_mfma_f32_16x16x16bf16_1k(a, b, c, 0, 0, 0);
#elif __has_builtin(__builtin_amdgcn_mfma_f32_16x16x16_bf16)
    return __builtin_amdgcn_mfma_f32_16x16x16_bf16(
        __builtin_bit_cast(bf16x4v, a), __builtin_bit_cast(bf16x4v, b), c, 0, 0, 0);
#else
    f32x4 d;
    asm volatile("v_mfma_f32_16x16x16_bf16 %0, %1, %2, %3"
                 : "=v"(d)
                 : "v"(a), "v"(b), "v"(c));
    return d;
#endif
}

// ---------- async global->LDS, 16B per lane ----------
__device__ __forceinline__ void gl_lds16(const void* g, void* l) {
    typedef const unsigned int __attribute__((address_space(1))) * gp_t;
    typedef unsigned int __attribute__((address_space(3))) * lp_t;
    __builtin_amdgcn_global_load_lds((gp_t)(unsigned long long)g,
                                     (lp_t)(unsigned int)(unsigned long long)l,
                                     16, 0, 0);
}

// ---------- cheap exact-enough GELU (tanh-form; max dev ~3e-4) ----------
__device__ __forceinline__ float gelu_fast(float v) {
    float u = 1.5957691216f * (v + 0.044715f * v * v * v);
    return v / (1.f + __expf(-u));
}

// Q-side scale: 1/sqrt(64) * log2(e) folded into wq and bq so attention
// softmax can use raw v_exp_f32 (2^x) with no per-element multiply.
#define QSCALE 0.1803368801111244f

// =====================================================================
// Unified weight prep (one launch): grid (128, 32, 6).
//  z 0..3: 1024x1024 transpose+bf16 (x<32 active; z==0,x in [32,44): bias)
//          mode 1 = rotary*QSCALE (wq), 2 = rotary (wk), 0 = plain
//  z 4: w1 [1024,4096] -> w1T[4096,1024]
//  z 5: w2 [4096,1024] -> w2T[1024,4096]
// Rotary is linear: fold column-difference (within 64-wide head) into W.
// =====================================================================
__global__ __launch_bounds__(256) void prep_weights(TW6 io) {
    const int z = blockIdx.z, bx = blockIdx.x, by = blockIdx.y;
    const float* W; u16* Wt; int mode = 0, N_, K_, n0, k0;
    if (z < 4) {
        if (bx >= 32) {
            if (z == 0 && bx < 44 && by == 0) {
                const int i = (bx - 32) * 256 + threadIdx.x;  // 0..3071
                const int d = i & 1023;
                const int dp = (d & ~63) | ((d + 63) & 63);
                float v;
                if (i < 1024) v = QSCALE * (io.bq[d] - io.bq[dp]);
                else if (i < 2048) v = io.bk[d] - io.bk[dp];
                else v = io.bv[d];
                io.bqkv[i] = v;
            }
            return;
        }
        W = io.w[z]; Wt = io.o[z]; mode = io.mode[z];
        N_ = 1024; K_ = 1024; n0 = bx * 32; k0 = by * 32;
    } else if (z == 4) {
        W = io.w[4]; Wt = io.o[4]; N_ = 4096; K_ = 1024; n0 = bx * 32; k0 = by * 32;
    } else {
        W = io.w[5]; Wt = io.o[5]; N_ = 1024; K_ = 4096; n0 = by * 32; k0 = bx * 32;
    }
    __shared__ u16 tile[32][33];
    const int tx = threadIdx.x & 31, ty = threadIdx.x >> 5;
    const int n = n0 + tx;
    const int np = (n & ~63) | ((n + 63) & 63);
    const float s = (mode == 1) ? QSCALE : 1.f;
#pragma unroll
    for (int i = 0; i < 32; i += 8) {
        const size_t r = (size_t)(k0 + ty + i) * N_;
        float v = W[r + n];
        if (mode) v = (v - W[r + np]) * s;
        tile[ty + i][tx] = f2b(v);
    }
    __syncthreads();
#pragma unroll
    for (int i = 0; i < 32; i += 8)
        Wt[(size_t)(n0 + ty + i) * K_ + k0 + tx] = tile[tx][ty + i];
}

// =====================================================================
// V transpose: qkv[b*2048+n][2048+h*64+d] -> vT[(bh)*64+d][n] (per-head)
// =====================================================================
__global__ __launch_bounds__(256) void transpose_v(const u16* __restrict__ qkv,
                                                   u16* __restrict__ vT) {
    __shared__ u16 tile[32][33];
    const int tx = threadIdx.x & 31, ty = threadIdx.x >> 5;
    const int n0 = blockIdx.x * 32, d0 = blockIdx.y * 32, bh = blockIdx.z;
    const int b = bh >> 4, h = bh & 15;
#pragma unroll
    for (int i = 0; i < 32; i += 8)
        tile[ty + i][tx] =
            qkv[(size_t)(b * 2048 + n0 + ty + i) * 3072 + 2048 + h * 64 + d0 + tx];
    __syncthreads();
#pragma unroll
    for (int i = 0; i < 32; i += 8)
        vT[((size_t)bh * 64 + d0 + ty + i) * 2048 + n0 + tx] = tile[tx][ty + i];
}

// =====================================================================
// RMSNorm: fp32 in [rows, 1024] -> bf16 out
// =====================================================================
__global__ __launch_bounds__(256) void rmsnorm_kernel(const float* __restrict__ x,
                                                      const float* __restrict__ scale,
                                                      u16* __restrict__ out) {
    __shared__ float red[4];
    const int t = threadIdx.x, row = blockIdx.x;
    const float4* xr = (const float4*)(x + (size_t)row * 1024);
    float4 v = xr[t];
    float ss = v.x * v.x + v.y * v.y + v.z * v.z + v.w * v.w;
#pragma unroll
    for (int off = 1; off < 64; off <<= 1) ss += __shfl_xor(ss, off);
    if ((t & 63) == 0) red[t >> 6] = ss;
    __syncthreads();
    float tot = red[0] + red[1] + red[2] + red[3];
    float inv = 1.f / (sqrtf(tot * (1.f / 1024.f)) + 1e-8f);
    const float4* sr = (const float4*)scale;
    float4 s = sr[t];
    u16x4 o;
    o[0] = f2b(v.x * inv * s.x);
    o[1] = f2b(v.y * inv * s.y);
    o[2] = f2b(v.z * inv * s.z);
    o[3] = f2b(v.w * inv * s.w);
    ((u16x4*)(out + (size_t)row * 1024))[t] = o;
}

// =====================================================================
// bf16 MFMA GEMM, 128x128 tile, BK=64 (half the barriers of BK=32 for
// short-K GEMMs), 4 waves (2x2 of 64x64), 32 KB LDS.
// 8-chunk XOR swizzle: logical chunk k of row r lives at slot k^(r&7)
// -> b128 fragment reads 2-way (free); staging dest stays lane*16.
// EPI: 0 = bf16(AB+bias); 1 = f32(AB+bias+resid); 2 = bf16(gelu(AB+bias))
// =====================================================================
template <int EPI>
__global__ __launch_bounds__(256) void gemm_kernel(const u16* __restrict__ A,
                                                   const u16* __restrict__ Bt,
                                                   const float* __restrict__ bias,
                                                   const float* __restrict__ resid,
                                                   void* __restrict__ outp,
                                                   int M, int N, int K) {
    __shared__ __align__(16) u16 As[128 * 64];
    __shared__ __align__(16) u16 Bs[128 * 64];
    const int t = threadIdx.x, lane = t & 63;
    const int w = t >> 6, wm = (w >> 1) * 64, wn = (w & 1) * 64;
    const int c = lane & 15, qd = lane >> 4;
    const int n0 = blockIdx.x * 128, m0 = blockIdx.y * 128;

    const int srow = t >> 3;                          // 0..31
    const int sch8 = ((t & 7) ^ (srow & 7)) * 8;      // swizzled source col
    const u16* Ag = A + (size_t)(m0 + srow) * K + sch8;
    const u16* Bg = Bt + (size_t)(n0 + srow) * K + sch8;
    const size_t rstride = (size_t)32 * K;

    f32x4 acc[4][4] = {};
    for (int kt = 0; kt < K; kt += 64) {
        __syncthreads();
#pragma unroll
        for (int g = 0; g < 4; g++) {
            gl_lds16(Ag + g * rstride, &As[t * 8 + g * 2048]);
            gl_lds16(Bg + g * rstride, &Bs[t * 8 + g * 2048]);
        }
        Ag += 64;
        Bg += 64;
        __syncthreads();
#pragma unroll
        for (int s = 0; s < 2; s++) {
            s16x8 a[4], b[4];
#pragma unroll
            for (int im = 0; im < 4; im++)
                a[im] = *(const s16x8*)&As[(wm + im * 16 + c) * 64 +
                                           (((s * 4 + qd) ^ (c & 7)) * 8)];
#pragma unroll
            for (int jn = 0; jn < 4; jn++)
                b[jn] = *(const s16x8*)&Bs[(wn + jn * 16 + c) * 64 +
                                           (((s * 4 + qd) ^ (c & 7)) * 8)];
#pragma unroll
            for (int im = 0; im < 4; im++)
#pragma unroll
                for (int jn = 0; jn < 4; jn++)
                    acc[im][jn] = mfma16(a[im], b[jn], acc[im][jn]);
        }
    }

#pragma unroll
    for (int im = 0; im < 4; im++) {
#pragma unroll
        for (int jn = 0; jn < 4; jn++) {
            const int colg = n0 + wn + jn * 16 + c;
            const float bv = bias[colg];
#pragma unroll
            for (int r = 0; r < 4; r++) {
                const int rowg = m0 + wm + im * 16 + qd * 4 + r;
                const size_t off = (size_t)rowg * N + colg;
                float v = acc[im][jn][r] + bv;
                if (EPI == 0) {
                    ((u16*)outp)[off] = f2b(v);
                } else if (EPI == 1) {
                    ((float*)outp)[off] = v + resid[off];
                } else {
                    ((u16*)outp)[off] = f2b(gelu_fast(v));
                }
            }
        }
    }
}

// =====================================================================
// Split-K GEMM, BK=64 (same swizzle): blockIdx.z = split; fp32 partials.
// =====================================================================
__global__ __launch_bounds__(256) void gemm_splitk(const u16* __restrict__ A,
                                                   const u16* __restrict__ Bt,
                                                   Ptr4 parts,
                                                   int N, int Ktot, int Kc) {
    __shared__ __align__(16) u16 As[128 * 64];
    __shared__ __align__(16) u16 Bs[128 * 64];
    const int t = threadIdx.x, lane = t & 63;
    const int w = t >> 6, wm = (w >> 1) * 64, wn = (w & 1) * 64;
    const int c = lane & 15, qd = lane >> 4;
    const int n0 = blockIdx.x * 128, m0 = blockIdx.y * 128;
    const int z = blockIdx.z;
    float* out = parts.p[z];

    const int srow = t >> 3;
    const int sch8 = ((t & 7) ^ (srow & 7)) * 8;
    const u16* Ag = A + (size_t)(m0 + srow) * Ktot + z * Kc + sch8;
    const u16* Bg = Bt + (size_t)(n0 + srow) * Ktot + z * Kc + sch8;
    const size_t rstride = (size_t)32 * Ktot;

    f32x4 acc[4][4] = {};
    for (int kt = 0; kt < Kc; kt += 64) {
        __syncthreads();
#pragma unroll
        for (int g = 0; g < 4; g++) {
            gl_lds16(Ag + g * rstride, &As[t * 8 + g * 2048]);
            gl_lds16(Bg + g * rstride, &Bs[t * 8 + g * 2048]);
        }
        Ag += 64;
        Bg += 64;
        __syncthreads();
#pragma unroll
        for (int s = 0; s < 2; s++) {
            s16x8 a[4], b[4];
#pragma unroll
            for (int im = 0; im < 4; im++)
                a[im] = *(const s16x8*)&As[(wm + im * 16 + c) * 64 +
                                           (((s * 4 + qd) ^ (c & 7)) * 8)];
#pragma unroll
            for (int jn = 0; jn < 4; jn++)
                b[jn] = *(const s16x8*)&Bs[(wn + jn * 16 + c) * 64 +
                                           (((s * 4 + qd) ^ (c & 7)) * 8)];
#pragma unroll
            for (int im = 0; im < 4; im++)
#pragma unroll
                for (int jn = 0; jn < 4; jn++)
                    acc[im][jn] = mfma16(a[im], b[jn], acc[im][jn]);
        }
    }

#pragma unroll
    for (int im = 0; im < 4; im++)
#pragma unroll
        for (int jn = 0; jn < 4; jn++) {
            const int colg = n0 + wn + jn * 16 + c;
#pragma unroll
            for (int r = 0; r < 4; r++) {
                const int rowg = m0 + wm + im * 16 + qd * 4 + r;
                out[(size_t)rowg * N + colg] = acc[im][jn][r];
            }
        }
}

// =====================================================================
// Split-K reduce. One block per row (1024 cols, float4/thread).
// =====================================================================
template <int S, bool NORM>
__global__ __launch_bounds__(256) void reduce_kernel(Ptr4 parts,
                                                     const float* __restrict__ bias,
                                                     const float* __restrict__ resid,
                                                     const float* __restrict__ scale,
                                                     float* __restrict__ yout,
                                                     u16* __restrict__ xnout) {
    __shared__ float red[4];
    const int t = threadIdx.x, row = blockIdx.x;
    const size_t base = (size_t)row * 1024;
    float4 v = ((const float4*)(resid + base))[t];
    float4 bv = ((const float4*)bias)[t];
    v.x += bv.x; v.y += bv.y; v.z += bv.z; v.w += bv.w;
#pragma unroll
    for (int s = 0; s < S; s++) {
        float4 pv = ((const float4*)(parts.p[s] + base))[t];
        v.x += pv.x; v.y += pv.y; v.z += pv.z; v.w += pv.w;
    }
    ((float4*)(yout + base))[t] = v;
    if (NORM) {
        float ss = v.x * v.x + v.y * v.y + v.z * v.z + v.w * v.w;
#pragma unroll
        for (int off = 1; off < 64; off <<= 1) ss += __shfl_xor(ss, off);
        if ((t & 63) == 0) red[t >> 6] = ss;
        __syncthreads();
        float tot = red[0] + red[1] + red[2] + red[3];
        float inv = 1.f / (sqrtf(tot * (1.f / 1024.f)) + 1e-8f);
        float4 s = ((const float4*)scale)[t];
        u16x4 o;
        o[0] = f2b(v.x * inv * s.x);
        o[1] = f2b(v.y * inv * s.y);
        o[2] = f2b(v.z * inv * s.z);
        o[3] = f2b(v.w * inv * s.w);
        ((u16x4*)(xnout + base))[t] = o;
    }
}

// =====================================================================
// Flash attention v9: BARRIER-FREE main loop. k-split across waves
// (wave w owns k rows [16w,16w+16) of each 64-KV tile); each wave's
// K and V fragments are loaded DIRECTLY global->registers (L2-resident,
// 4% HBM). No LDS, no gl_lds, no __syncthreads for all 32 iterations:
// compiler emits exact counted vmcnt per register load (T4 semantics,
// per-wave legal). K frags depth-1 prefetched (kfA/kfB static dbuf);
// V frags issued at iter top, consumed ~300cy later after QK+softmax.
// Waves drift freely -> MFMA/VALU/trans pipes mix across 12 waves/CU.
// LDS only in the once-per-block epilogue (k-slice reduction).
// =====================================================================
__global__ __launch_bounds__(256, 3) void attn_kernel(const u16* __restrict__ qkv,
                                                      const u16* __restrict__ vT,
                                                      u16* __restrict__ attn) {
    __shared__ __align__(16) char smem[16896];  // SC f32[64][66] / OT u16[64][72]
    __shared__ float LS[4][64];

    const int t = threadIdx.x, lane = t & 63, w = t >> 6;
    const int c = lane & 15, g = lane >> 4;

    // XCD-grouped bijective swizzle: 1024 blocks, 8 XCDs, 128 blocks/XCD.
    const int id = blockIdx.x;
    const int logical = (id & 7) * 128 + (id >> 3);
    const int bh = logical >> 5, qb = logical & 31;
    const int b = bh >> 4, h = bh & 15;
    const int q0 = qb * 64;
    const size_t rowbase = (size_t)b * 2048;

    // Per-lane global fragment pointers.
    // kf (A-frag of swapped QK^T): lane (c,g): K row it*64+16w+c, d = ks*32+g*8..+7
    const u16* kfp = qkv + (rowbase + w * 16 + c) * 3072 + 1024 + h * 64 + g * 8;
    // vf (A-frag of PV): lane (c,g): vT[bh*64 + im*16+c][it*64 + 16w + 4g..+3]
    const u16* vfp = vT + ((size_t)bh * 64 + c) * 2048 + w * 16 + g * 4;

    // Q B-fragments hoisted: qf[jn][ks] covers all 64 q rows of the block.
    s16x8 qf[4][2];
    {
        const u16* qg = qkv + (rowbase + q0) * 3072 + h * 64;
#pragma unroll
        for (int jn = 0; jn < 4; jn++)
#pragma unroll
            for (int ks = 0; ks < 2; ks++)
                qf[jn][ks] = *(const s16x8*)&qg[(size_t)(jn * 16 + c) * 3072 +
                                                ks * 32 + g * 8];
    }

    f32x4 acc[4][4] = {};   // O^T partial: [im: d-tile][jn: q-tile]
    float ls[4] = {};       // lane-local lsum partial per q-tile

    s16x8 kfA[2], kfB[2];
    s16x4 vf[4];

    auto loadK = [&](s16x8 (&dst)[2], int it) {
        const u16* p = kfp + (size_t)it * 64 * 3072;
        dst[0] = *(const s16x8*)p;
        dst[1] = *(const s16x8*)(p + 32);
    };
    auto loadV = [&](int it) {
#pragma unroll
        for (int im = 0; im < 4; im++)
            vf[im] = *(const s16x4*)(vfp + (size_t)(im * 16) * 2048 + it * 64);
    };
    auto compute = [&](s16x8 (&kf_)[2]) {
        f32x4 sc[4] = {};
        __builtin_amdgcn_s_setprio(1);
#pragma unroll
        for (int ks = 0; ks < 2; ks++)
#pragma unroll
            for (int jn = 0; jn < 4; jn++)
                sc[jn] = mfma16(kf_[ks], qf[jn][ks], sc[jn]);
        __builtin_amdgcn_s_setprio(0);
        s16x4 pb[4];
#pragma unroll
        for (int jn = 0; jn < 4; jn++) {
            float p0 = exp2_fast(sc[jn][0]);
            float p1 = exp2_fast(sc[jn][1]);
            float p2 = exp2_fast(sc[jn][2]);
            float p3 = exp2_fast(sc[jn][3]);
            ls[jn] += (p0 + p1) + (p2 + p3);
            pb[jn][0] = f2b(p0); pb[jn][1] = f2b(p1);
            pb[jn][2] = f2b(p2); pb[jn][3] = f2b(p3);
        }
        __builtin_amdgcn_s_setprio(1);
#pragma unroll
        for (int im = 0; im < 4; im++)
#pragma unroll
            for (int jn = 0; jn < 4; jn++)
                acc[im][jn] = mfma16k16(vf[im], pb[jn], acc[im][jn]);
        __builtin_amdgcn_s_setprio(0);
    };

    loadK(kfA, 0);
    for (int t2 = 0; t2 < 16; ++t2) {
        const int it0 = t2 * 2;
        loadK(kfB, it0 + 1);   // prefetch next K slice
        loadV(it0);            // V for this iter (consumed after QK+softmax)
        compute(kfA);
        if (t2 < 15) loadK(kfA, it0 + 2);
        loadV(it0 + 1);
        compute(kfB);
    }

    // lsum: reduce across lane groups (k within slice), publish per wave
#pragma unroll
    for (int jn = 0; jn < 4; jn++) {
        float v = ls[jn];
        v += __shfl_xor(v, 16);
        v += __shfl_xor(v, 32);
        ls[jn] = v;
    }
    if (lane < 16) {
#pragma unroll
        for (int jn = 0; jn < 4; jn++) LS[w][jn * 16 + lane] = ls[jn];
    }

    // sequential k-slice reduction of O^T into wave 0 (scratch = smem)
    float* SC = (float*)smem;  // [64][66] f32
#pragma unroll
    for (int src = 3; src >= 1; --src) {
        __syncthreads();
        if (w == src) {
#pragma unroll
            for (int im = 0; im < 4; im++)
#pragma unroll
                for (int jn = 0; jn < 4; jn++)
#pragma unroll
                    for (int r = 0; r < 4; r++)
                        SC[(im * 16 + g * 4 + r) * 66 + jn * 16 + c] =
                            acc[im][jn][r];
        }
        __syncthreads();
        if (w == src - 1) {
#pragma unroll
            for (int im = 0; im < 4; im++)
#pragma unroll
                for (int jn = 0; jn < 4; jn++)
#pragma unroll
                    for (int r = 0; r < 4; r++)
                        acc[im][jn][r] +=
                            SC[(im * 16 + g * 4 + r) * 66 + jn * 16 + c];
        }
    }
    __syncthreads();

    // wave 0: scale by 1/lsum, write q-major tile for coalesced store
    u16* OT = (u16*)smem;  // [64][72] u16
    if (w == 0) {
#pragma unroll
        for (int jn = 0; jn < 4; jn++) {
            const int q = jn * 16 + c;
            const float inv = 1.f / (LS[0][q] + LS[1][q] + LS[2][q] + LS[3][q]);
#pragma unroll
            for (int im = 0; im < 4; im++)
#pragma unroll
                for (int r = 0; r < 4; r++)
                    OT[q * 72 + im * 16 + g * 4 + r] = f2b(acc[im][jn][r] * inv);
        }
    }
    __syncthreads();

    // coalesced store: thread t -> q = t>>2, d-chunk = (t&3)*16
    {
        const int q = t >> 2, d0 = (t & 3) * 16;
        const int grow = b * 2048 + q0 + q;
        u16* dst = attn + (size_t)grow * 1024 + h * 64 + d0;
        *(s16x8*)dst = *(const s16x8*)&OT[q * 72 + d0];
        *((s16x8*)dst + 1) = *((const s16x8*)&OT[q * 72 + d0] + 1);
    }
}

// =====================================================================
extern "C" void kernel_launch(void* const* d_in, const int* in_sizes, int n_in,
                              void* d_out, int out_size, void* d_ws, size_t ws_size,
                              hipStream_t stream) {
    const float* x = (const float*)d_in[0];
    const float* wq = (const float*)d_in[1];
    const float* bq = (const float*)d_in[2];
    const float* wk = (const float*)d_in[3];
    const float* bk = (const float*)d_in[4];
    const float* wv = (const float*)d_in[5];
    const float* bv = (const float*)d_in[6];
    const float* wo = (const float*)d_in[7];
    const float* bo = (const float*)d_in[8];
    const float* scale1 = (const float*)d_in[9];
    const float* scale2 = (const float*)d_in[10];
    const float* w1 = (const float*)d_in[11];
    const float* b1 = (const float*)d_in[12];
    const float* w2 = (const float*)d_in[13];
    const float* b2 = (const float*)d_in[14];
    float* out = (float*)d_out;

    char* ws = (char*)d_ws;
    size_t off = 0;
    auto alloc = [&](size_t bytes) -> char* {
        char* p = ws + off;
        off += (bytes + 255) & ~(size_t)255;
        return p;
    };
    u16* wqkvT = (u16*)alloc((size_t)3072 * 1024 * 2);   //  6 MB  [ws+0]
    u16* woT   = (u16*)alloc((size_t)1024 * 1024 * 2);   //  2 MB
    u16* w1T   = (u16*)alloc((size_t)4096 * 1024 * 2);   //  8 MB
    u16* w2T   = (u16*)alloc((size_t)1024 * 4096 * 2);   //  8 MB
    float* bqkv = (float*)alloc(3072 * 4);
    u16* xn    = (u16*)alloc((size_t)4096 * 1024 * 2);   //  8 MB
    u16* qkv   = (u16*)alloc((size_t)4096 * 3072 * 2);   // 24 MB
    u16* vT    = (u16*)alloc((size_t)32 * 64 * 2048 * 2);//  8 MB
    u16* attnb = (u16*)alloc((size_t)4096 * 1024 * 2);   //  8 MB
    float* y1  = (float*)alloc((size_t)4096 * 1024 * 4); // 16 MB
    u16* hbuf  = (u16*)alloc((size_t)4096 * 4096 * 2);   // 32 MB

    const size_t SPLIT = (size_t)4096 * 1024;
    Ptr4 po; po.p[0] = (float*)qkv; po.p[1] = (float*)qkv + SPLIT;
    po.p[2] = nullptr; po.p[3] = nullptr;
    Ptr4 pf; pf.p[0] = (float*)xn; pf.p[1] = (float*)xn + SPLIT;
    pf.p[2] = (float*)xn + 2 * SPLIT; pf.p[3] = (float*)wqkvT;

    dim3 blk(256);

    TW6 tw;
    tw.w[0] = wq; tw.o[0] = wqkvT;                          tw.mode[0] = 1;
    tw.w[1] = wk; tw.o[1] = wqkvT + (size_t)1024 * 1024;    tw.mode[1] = 2;
    tw.w[2] = wv; tw.o[2] = wqkvT + (size_t)2048 * 1024;    tw.mode[2] = 0;
    tw.w[3] = wo; tw.o[3] = woT;                            tw.mode[3] = 0;
    tw.w[4] = w1; tw.o[4] = w1T;                            tw.mode[4] = 0;
    tw.w[5] = w2; tw.o[5] = w2T;                            tw.mode[5] = 0;
    tw.bq = bq; tw.bk = bk; tw.bv = bv; tw.bqkv = bqkv;
    prep_weights<<<dim3(128, 32, 6), blk, 0, stream>>>(tw);

    // 1. RMSNorm1
    rmsnorm_kernel<<<4096, blk, 0, stream>>>(x, scale1, xn);
    // 2. QKV GEMM (rotary + log2e pre-folded into weights/bias) -> qkv bf16
    gemm_kernel<0><<<dim3(24, 32), blk, 0, stream>>>(xn, wqkvT, bqkv, nullptr, qkv, 4096, 3072, 1024);
    // 3. per-head V transpose
    transpose_v<<<dim3(64, 2, 32), blk, 0, stream>>>(qkv, vT);
    // 4. flash attention v9 (barrier-free, regs-only main loop)
    attn_kernel<<<dim3(1024), blk, 0, stream>>>(qkv, vT, attnb);
    // 5. O-proj split-K=2
    gemm_splitk<<<dim3(8, 32, 2), blk, 0, stream>>>(attnb, woT, po, 1024, 1024, 512);
    // 6. reduce + bias + resid + RMSNorm2 -> y1 fp32, xn bf16
    reduce_kernel<2, true><<<4096, blk, 0, stream>>>(po, bo, x, scale2, y1, xn);
    // 7. FFN1 + fast exact GELU -> hbuf bf16
    gemm_kernel<2><<<dim3(32, 32), blk, 0, stream>>>(xn, w1T, b1, nullptr, hbuf, 4096, 4096, 1024);
    // 8. FFN2 split-K=4
    gemm_splitk<<<dim3(8, 32, 4), blk, 0, stream>>>(hbuf, w2T, pf, 1024, 4096, 1024);
    // 9. reduce + bias + resid -> out fp32
    reduce_kernel<4, false><<<4096, blk, 0, stream>>>(pf, b2, y1, nullptr, out, nullptr);
}

// Round 5
// 373.604 us; speedup vs baseline: 1.1379x; 1.1379x over previous
//
#include <hip/hip_runtime.h>
#include <hip/hip_bf16.h>
#include <math.h>

typedef unsigned short u16;
typedef short s16x8 __attribute__((ext_vector_type(8)));
typedef short s16x4 __attribute__((ext_vector_type(4)));
typedef __bf16 bf16x8v __attribute__((ext_vector_type(8)));
typedef __bf16 bf16x4v __attribute__((ext_vector_type(4)));
typedef float f32x4 __attribute__((ext_vector_type(4)));
typedef unsigned short u16x4 __attribute__((ext_vector_type(4)));

struct Ptr4 { float* p[4]; };
struct TW6 {
    const float* w[6]; u16* o[6]; int mode[6];
    const float *bq, *bk, *bv; float* bqkv;
};

// ---------- conversions ----------
__device__ __forceinline__ u16 f2b(float f) {
    __hip_bfloat16 h = __float2bfloat16(f);
    return __builtin_bit_cast(u16, h);
}

// ---------- raw v_exp_f32 (2^x) with portable fallback ----------
__device__ __forceinline__ float exp2_fast(float x) {
#if __has_builtin(__builtin_amdgcn_exp2f)
    return __builtin_amdgcn_exp2f(x);
#else
    return exp2f(x);
#endif
}

// ---------- MFMA wrappers ----------
__device__ __forceinline__ f32x4 mfma16(s16x8 a, s16x8 b, f32x4 c) {
    return __builtin_amdgcn_mfma_f32_16x16x32_bf16(
        __builtin_bit_cast(bf16x8v, a), __builtin_bit_cast(bf16x8v, b), c, 0, 0, 0);
}

// 16x16x16 bf16 (K=16) — operands 4 bf16/lane (2 VGPR).
__device__ __forceinline__ f32x4 mfma16k16(s16x4 a, s16x4 b, f32x4 c) {
#if __has_builtin(__builtin_amdgcn_mfma_f32_16x16x16bf16_1k)
    return __builtin_amdgcn_mfma_f32_16x16x16bf16_1k(a, b, c, 0, 0, 0);
#elif __has_builtin(__builtin_amdgcn_mfma_f32_16x16x16_bf16)
    return __builtin_amdgcn_mfma_f32_16x16x16_bf16(
        __builtin_bit_cast(bf16x4v, a), __builtin_bit_cast(bf16x4v, b), c, 0, 0, 0);
#else
    f32x4 d;
    asm volatile("v_mfma_f32_16x16x16_bf16 %0, %1, %2, %3"
                 : "=v"(d)
                 : "v"(a), "v"(b), "v"(c));
    return d;
#endif
}

// ---------- async global->LDS, 16B per lane ----------
__device__ __forceinline__ void gl_lds16(const void* g, void* l) {
    typedef const unsigned int __attribute__((address_space(1))) * gp_t;
    typedef unsigned int __attribute__((address_space(3))) * lp_t;
    __builtin_amdgcn_global_load_lds((gp_t)(unsigned long long)g,
                                     (lp_t)(unsigned int)(unsigned long long)l,
                                     16, 0, 0);
}

// ---------- cheap exact-enough GELU (tanh-form; max dev ~3e-4) ----------
__device__ __forceinline__ float gelu_fast(float v) {
    float u = 1.5957691216f * (v + 0.044715f * v * v * v);
    return v / (1.f + __expf(-u));
}

// Q-side scale: 1/sqrt(64) * log2(e) folded into wq and bq so attention
// softmax can use raw v_exp_f32 (2^x) with no per-element multiply.
#define QSCALE 0.1803368801111244f

// =====================================================================
// Unified weight prep (one launch): grid (128, 32, 6).
//  z 0..3: 1024x1024 transpose+bf16 (x<32 active; z==0,x in [32,44): bias)
//          mode 1 = rotary*QSCALE (wq), 2 = rotary (wk), 0 = plain
//  z 4: w1 [1024,4096] -> w1T[4096,1024]
//  z 5: w2 [4096,1024] -> w2T[1024,4096]
// Rotary is linear: fold column-difference (within 64-wide head) into W.
// =====================================================================
__global__ __launch_bounds__(256) void prep_weights(TW6 io) {
    const int z = blockIdx.z, bx = blockIdx.x, by = blockIdx.y;
    const float* W; u16* Wt; int mode = 0, N_, K_, n0, k0;
    if (z < 4) {
        if (bx >= 32) {
            if (z == 0 && bx < 44 && by == 0) {
                const int i = (bx - 32) * 256 + threadIdx.x;  // 0..3071
                const int d = i & 1023;
                const int dp = (d & ~63) | ((d + 63) & 63);
                float v;
                if (i < 1024) v = QSCALE * (io.bq[d] - io.bq[dp]);
                else if (i < 2048) v = io.bk[d] - io.bk[dp];
                else v = io.bv[d];
                io.bqkv[i] = v;
            }
            return;
        }
        W = io.w[z]; Wt = io.o[z]; mode = io.mode[z];
        N_ = 1024; K_ = 1024; n0 = bx * 32; k0 = by * 32;
    } else if (z == 4) {
        W = io.w[4]; Wt = io.o[4]; N_ = 4096; K_ = 1024; n0 = bx * 32; k0 = by * 32;
    } else {
        W = io.w[5]; Wt = io.o[5]; N_ = 1024; K_ = 4096; n0 = by * 32; k0 = bx * 32;
    }
    __shared__ u16 tile[32][33];
    const int tx = threadIdx.x & 31, ty = threadIdx.x >> 5;
    const int n = n0 + tx;
    const int np = (n & ~63) | ((n + 63) & 63);
    const float s = (mode == 1) ? QSCALE : 1.f;
#pragma unroll
    for (int i = 0; i < 32; i += 8) {
        const size_t r = (size_t)(k0 + ty + i) * N_;
        float v = W[r + n];
        if (mode) v = (v - W[r + np]) * s;
        tile[ty + i][tx] = f2b(v);
    }
    __syncthreads();
#pragma unroll
    for (int i = 0; i < 32; i += 8)
        Wt[(size_t)(n0 + ty + i) * K_ + k0 + tx] = tile[tx][ty + i];
}

// =====================================================================
// V transpose: qkv[b*2048+n][2048+h*64+d] -> vT[(bh)*64+d][n] (per-head)
// =====================================================================
__global__ __launch_bounds__(256) void transpose_v(const u16* __restrict__ qkv,
                                                   u16* __restrict__ vT) {
    __shared__ u16 tile[32][33];
    const int tx = threadIdx.x & 31, ty = threadIdx.x >> 5;
    const int n0 = blockIdx.x * 32, d0 = blockIdx.y * 32, bh = blockIdx.z;
    const int b = bh >> 4, h = bh & 15;
#pragma unroll
    for (int i = 0; i < 32; i += 8)
        tile[ty + i][tx] =
            qkv[(size_t)(b * 2048 + n0 + ty + i) * 3072 + 2048 + h * 64 + d0 + tx];
    __syncthreads();
#pragma unroll
    for (int i = 0; i < 32; i += 8)
        vT[((size_t)bh * 64 + d0 + ty + i) * 2048 + n0 + tx] = tile[tx][ty + i];
}

// =====================================================================
// RMSNorm: fp32 in [rows, 1024] -> bf16 out
// =====================================================================
__global__ __launch_bounds__(256) void rmsnorm_kernel(const float* __restrict__ x,
                                                      const float* __restrict__ scale,
                                                      u16* __restrict__ out) {
    __shared__ float red[4];
    const int t = threadIdx.x, row = blockIdx.x;
    const float4* xr = (const float4*)(x + (size_t)row * 1024);
    float4 v = xr[t];
    float ss = v.x * v.x + v.y * v.y + v.z * v.z + v.w * v.w;
#pragma unroll
    for (int off = 1; off < 64; off <<= 1) ss += __shfl_xor(ss, off);
    if ((t & 63) == 0) red[t >> 6] = ss;
    __syncthreads();
    float tot = red[0] + red[1] + red[2] + red[3];
    float inv = 1.f / (sqrtf(tot * (1.f / 1024.f)) + 1e-8f);
    const float4* sr = (const float4*)scale;
    float4 s = sr[t];
    u16x4 o;
    o[0] = f2b(v.x * inv * s.x);
    o[1] = f2b(v.y * inv * s.y);
    o[2] = f2b(v.z * inv * s.z);
    o[3] = f2b(v.w * inv * s.w);
    ((u16x4*)(out + (size_t)row * 1024))[t] = o;
}

// =====================================================================
// bf16 MFMA GEMM, 128x128 tile, BK=64 (half the barriers of BK=32 for
// short-K GEMMs), 4 waves (2x2 of 64x64), 32 KB LDS.
// 8-chunk XOR swizzle: logical chunk k of row r lives at slot k^(r&7)
// -> b128 fragment reads 2-way (free); staging dest stays lane*16.
// EPI: 0 = bf16(AB+bias); 1 = f32(AB+bias+resid); 2 = bf16(gelu(AB+bias))
// =====================================================================
template <int EPI>
__global__ __launch_bounds__(256) void gemm_kernel(const u16* __restrict__ A,
                                                   const u16* __restrict__ Bt,
                                                   const float* __restrict__ bias,
                                                   const float* __restrict__ resid,
                                                   void* __restrict__ outp,
                                                   int M, int N, int K) {
    __shared__ __align__(16) u16 As[128 * 64];
    __shared__ __align__(16) u16 Bs[128 * 64];
    const int t = threadIdx.x, lane = t & 63;
    const int w = t >> 6, wm = (w >> 1) * 64, wn = (w & 1) * 64;
    const int c = lane & 15, qd = lane >> 4;
    const int n0 = blockIdx.x * 128, m0 = blockIdx.y * 128;

    const int srow = t >> 3;                          // 0..31
    const int sch8 = ((t & 7) ^ (srow & 7)) * 8;      // swizzled source col
    const u16* Ag = A + (size_t)(m0 + srow) * K + sch8;
    const u16* Bg = Bt + (size_t)(n0 + srow) * K + sch8;
    const size_t rstride = (size_t)32 * K;

    f32x4 acc[4][4] = {};
    for (int kt = 0; kt < K; kt += 64) {
        __syncthreads();
#pragma unroll
        for (int g = 0; g < 4; g++) {
            gl_lds16(Ag + g * rstride, &As[t * 8 + g * 2048]);
            gl_lds16(Bg + g * rstride, &Bs[t * 8 + g * 2048]);
        }
        Ag += 64;
        Bg += 64;
        __syncthreads();
#pragma unroll
        for (int s = 0; s < 2; s++) {
            s16x8 a[4], b[4];
#pragma unroll
            for (int im = 0; im < 4; im++)
                a[im] = *(const s16x8*)&As[(wm + im * 16 + c) * 64 +
                                           (((s * 4 + qd) ^ (c & 7)) * 8)];
#pragma unroll
            for (int jn = 0; jn < 4; jn++)
                b[jn] = *(const s16x8*)&Bs[(wn + jn * 16 + c) * 64 +
                                           (((s * 4 + qd) ^ (c & 7)) * 8)];
#pragma unroll
            for (int im = 0; im < 4; im++)
#pragma unroll
                for (int jn = 0; jn < 4; jn++)
                    acc[im][jn] = mfma16(a[im], b[jn], acc[im][jn]);
        }
    }

#pragma unroll
    for (int im = 0; im < 4; im++) {
#pragma unroll
        for (int jn = 0; jn < 4; jn++) {
            const int colg = n0 + wn + jn * 16 + c;
            const float bv = bias[colg];
#pragma unroll
            for (int r = 0; r < 4; r++) {
                const int rowg = m0 + wm + im * 16 + qd * 4 + r;
                const size_t off = (size_t)rowg * N + colg;
                float v = acc[im][jn][r] + bv;
                if (EPI == 0) {
                    ((u16*)outp)[off] = f2b(v);
                } else if (EPI == 1) {
                    ((float*)outp)[off] = v + resid[off];
                } else {
                    ((u16*)outp)[off] = f2b(gelu_fast(v));
                }
            }
        }
    }
}

// =====================================================================
// Split-K GEMM, BK=64 (same swizzle): blockIdx.z = split; fp32 partials.
// =====================================================================
__global__ __launch_bounds__(256) void gemm_splitk(const u16* __restrict__ A,
                                                   const u16* __restrict__ Bt,
                                                   Ptr4 parts,
                                                   int N, int Ktot, int Kc) {
    __shared__ __align__(16) u16 As[128 * 64];
    __shared__ __align__(16) u16 Bs[128 * 64];
    const int t = threadIdx.x, lane = t & 63;
    const int w = t >> 6, wm = (w >> 1) * 64, wn = (w & 1) * 64;
    const int c = lane & 15, qd = lane >> 4;
    const int n0 = blockIdx.x * 128, m0 = blockIdx.y * 128;
    const int z = blockIdx.z;
    float* out = parts.p[z];

    const int srow = t >> 3;
    const int sch8 = ((t & 7) ^ (srow & 7)) * 8;
    const u16* Ag = A + (size_t)(m0 + srow) * Ktot + z * Kc + sch8;
    const u16* Bg = Bt + (size_t)(n0 + srow) * Ktot + z * Kc + sch8;
    const size_t rstride = (size_t)32 * Ktot;

    f32x4 acc[4][4] = {};
    for (int kt = 0; kt < Kc; kt += 64) {
        __syncthreads();
#pragma unroll
        for (int g = 0; g < 4; g++) {
            gl_lds16(Ag + g * rstride, &As[t * 8 + g * 2048]);
            gl_lds16(Bg + g * rstride, &Bs[t * 8 + g * 2048]);
        }
        Ag += 64;
        Bg += 64;
        __syncthreads();
#pragma unroll
        for (int s = 0; s < 2; s++) {
            s16x8 a[4], b[4];
#pragma unroll
            for (int im = 0; im < 4; im++)
                a[im] = *(const s16x8*)&As[(wm + im * 16 + c) * 64 +
                                           (((s * 4 + qd) ^ (c & 7)) * 8)];
#pragma unroll
            for (int jn = 0; jn < 4; jn++)
                b[jn] = *(const s16x8*)&Bs[(wn + jn * 16 + c) * 64 +
                                           (((s * 4 + qd) ^ (c & 7)) * 8)];
#pragma unroll
            for (int im = 0; im < 4; im++)
#pragma unroll
                for (int jn = 0; jn < 4; jn++)
                    acc[im][jn] = mfma16(a[im], b[jn], acc[im][jn]);
        }
    }

#pragma unroll
    for (int im = 0; im < 4; im++)
#pragma unroll
        for (int jn = 0; jn < 4; jn++) {
            const int colg = n0 + wn + jn * 16 + c;
#pragma unroll
            for (int r = 0; r < 4; r++) {
                const int rowg = m0 + wm + im * 16 + qd * 4 + r;
                out[(size_t)rowg * N + colg] = acc[im][jn][r];
            }
        }
}

// =====================================================================
// Split-K reduce. One block per row (1024 cols, float4/thread).
// =====================================================================
template <int S, bool NORM>
__global__ __launch_bounds__(256) void reduce_kernel(Ptr4 parts,
                                                     const float* __restrict__ bias,
                                                     const float* __restrict__ resid,
                                                     const float* __restrict__ scale,
                                                     float* __restrict__ yout,
                                                     u16* __restrict__ xnout) {
    __shared__ float red[4];
    const int t = threadIdx.x, row = blockIdx.x;
    const size_t base = (size_t)row * 1024;
    float4 v = ((const float4*)(resid + base))[t];
    float4 bv = ((const float4*)bias)[t];
    v.x += bv.x; v.y += bv.y; v.z += bv.z; v.w += bv.w;
#pragma unroll
    for (int s = 0; s < S; s++) {
        float4 pv = ((const float4*)(parts.p[s] + base))[t];
        v.x += pv.x; v.y += pv.y; v.z += pv.z; v.w += pv.w;
    }
    ((float4*)(yout + base))[t] = v;
    if (NORM) {
        float ss = v.x * v.x + v.y * v.y + v.z * v.z + v.w * v.w;
#pragma unroll
        for (int off = 1; off < 64; off <<= 1) ss += __shfl_xor(ss, off);
        if ((t & 63) == 0) red[t >> 6] = ss;
        __syncthreads();
        float tot = red[0] + red[1] + red[2] + red[3];
        float inv = 1.f / (sqrtf(tot * (1.f / 1024.f)) + 1e-8f);
        float4 s = ((const float4*)scale)[t];
        u16x4 o;
        o[0] = f2b(v.x * inv * s.x);
        o[1] = f2b(v.y * inv * s.y);
        o[2] = f2b(v.z * inv * s.z);
        o[3] = f2b(v.w * inv * s.w);
        ((u16x4*)(xnout + base))[t] = o;
    }
}

// =====================================================================
// Flash attention v10 = v8 (k-split waves, LDS-staged, P-in-registers)
// + counted-vmcnt pipeline (T3/T4): 3 KV buffers rotate; stage for tile
// t+2 always in flight; per-iter wait is s_waitcnt vmcnt(4) (only the
// 2-iterations-old stage must land) + raw s_barrier -- NEVER a full
// vmcnt(0) drain in the loop (that drain was the 62us plateau; m218:
// counted vs drain = +38..73%).
//  Hazards: stage(t+2) overwrites buf[t-1]; issued AFTER the barrier,
//  and all waves' compute(t-1) consumed its ds_reads before that
//  barrier (lgkmcnt(0) included in the wait). sched_barrier(0) pins
//  ds_reads below the barrier (rule 18).
// =====================================================================
__global__ __launch_bounds__(256, 3) void attn_kernel(const u16* __restrict__ qkv,
                                                      const u16* __restrict__ vT,
                                                      u16* __restrict__ attn) {
    // 3 buffers x (K 8KB + V 8KB) = 48 KB; epilogue reuses slab as
    // SC f32[64][66] (16.9 KB) and OT u16[64][72] (9.2 KB).
    __shared__ __align__(16) char smem[49152];
    __shared__ float LS[4][64];
    u16* SM = (u16*)smem;

    const int t = threadIdx.x, lane = t & 63, w = t >> 6;
    const int c = lane & 15, g = lane >> 4;

    // XCD-grouped bijective swizzle: 1024 blocks, 8 XCDs, 128 blocks/XCD.
    const int id = blockIdx.x;
    const int logical = (id & 7) * 128 + (id >> 3);
    const int bh = logical >> 5, qb = logical & 31;
    const int b = bh >> 4, h = bh & 15;
    const int q0 = qb * 64;
    const size_t rowbase = (size_t)b * 2048;

    const u16* kg = qkv + rowbase * 3072 + 1024 + h * 64;
    const u16* vg = vT + (size_t)bh * 64 * 2048;

    const int srow = t >> 3;
    const int sch = (t & 7) ^ (srow & 7);
    const u16* kptr = kg + (size_t)srow * 3072 + sch * 8;
    const u16* vptr = vg + (size_t)srow * 2048 + sch * 8;

    // stage KV tile `it` into buffer bi (4 gl_lds per thread)
    auto stage = [&](int it, int bi) {
        u16* B = SM + bi * 8192;
        const size_t ko = (size_t)it * 64 * 3072;
        const size_t vo = (size_t)it * 64;
        gl_lds16(kptr + ko, &B[t * 8]);
        gl_lds16(kptr + ko + (size_t)32 * 3072, &B[2048 + t * 8]);
        gl_lds16(vptr + vo, &B[4096 + t * 8]);
        gl_lds16(vptr + vo + (size_t)32 * 2048, &B[6144 + t * 8]);
    };

    // Q B-fragments hoisted: qf[jn][ks] covers all 64 q rows of the block.
    s16x8 qf[4][2];
    {
        const u16* qg = qkv + (rowbase + q0) * 3072 + h * 64;
#pragma unroll
        for (int jn = 0; jn < 4; jn++)
#pragma unroll
            for (int ks = 0; ks < 2; ks++)
                qf[jn][ks] = *(const s16x8*)&qg[(size_t)(jn * 16 + c) * 3072 +
                                                ks * 32 + g * 8];
    }

    stage(0, 0);
    stage(1, 1);

    f32x4 acc[4][4] = {};   // O^T partial: [im: d-tile][jn: q-tile]
    float ls[4] = {};       // lane-local lsum partial per q-tile
    const int kbase = w * 16;  // this wave's k-slice within the KV tile

    int cur = 0, nxt2 = 2;
    for (int it = 0; it < 32; it++) {
        // counted wait: only stage(it) (2 iters old) must have landed;
        // stage(it+1)'s 4 loads stay in flight across the barrier.
        if (it < 31)
            asm volatile("s_waitcnt vmcnt(4) lgkmcnt(0)" ::: "memory");
        else
            asm volatile("s_waitcnt vmcnt(0) lgkmcnt(0)" ::: "memory");
        __builtin_amdgcn_s_barrier();
        __builtin_amdgcn_sched_barrier(0);

        if (it + 2 < 32) stage(it + 2, nxt2);

        const u16* Kb = SM + cur * 8192;
        const u16* Vb = Kb + 4096;

        // K A-frags: rows kbase..kbase+15, full d=64 (2 ks steps of 32).
        s16x8 kf[2];
#pragma unroll
        for (int ks = 0; ks < 2; ks++)
            kf[ks] = *(const s16x8*)&Kb[(kbase + c) * 64 +
                                        (((ks * 4 + g) ^ (c & 7)) * 8)];
        // V^T A-frags: d-rows im*16+c, k-cols kbase+4g..+3 (b64 reads).
        s16x4 vf[4];
#pragma unroll
        for (int im = 0; im < 4; im++)
            vf[im] = *(const s16x4*)&Vb[(im * 16 + c) * 64 +
                                        (((2 * w + (g >> 1)) ^ (c & 7)) * 8) +
                                        (g & 1) * 4];

        // swapped QK^T: sc[jn] lane: q = jn*16+c, k = kbase + 4g + r
        f32x4 sc[4] = {};
        __builtin_amdgcn_s_setprio(1);
#pragma unroll
        for (int ks = 0; ks < 2; ks++)
#pragma unroll
            for (int jn = 0; jn < 4; jn++)
                sc[jn] = mfma16(kf[ks], qf[jn][ks], sc[jn]);
        __builtin_amdgcn_s_setprio(0);

        // softmax (no-max, exp2) + pack into PV B-fragments
        s16x4 pb[4];
#pragma unroll
        for (int jn = 0; jn < 4; jn++) {
            float p0 = exp2_fast(sc[jn][0]);
            float p1 = exp2_fast(sc[jn][1]);
            float p2 = exp2_fast(sc[jn][2]);
            float p3 = exp2_fast(sc[jn][3]);
            ls[jn] += (p0 + p1) + (p2 + p3);
            pb[jn][0] = f2b(p0); pb[jn][1] = f2b(p1);
            pb[jn][2] = f2b(p2); pb[jn][3] = f2b(p3);
        }

        // PV: O^T[d][q] += V^T(d x k16) * P^T(k16 x q)
        __builtin_amdgcn_s_setprio(1);
#pragma unroll
        for (int im = 0; im < 4; im++)
#pragma unroll
            for (int jn = 0; jn < 4; jn++)
                acc[im][jn] = mfma16k16(vf[im], pb[jn], acc[im][jn]);
        __builtin_amdgcn_s_setprio(0);

        cur = (cur == 2) ? 0 : cur + 1;
        nxt2 = (nxt2 == 2) ? 0 : nxt2 + 1;
    }

    // lsum: reduce across lane groups (k within slice), publish per wave
#pragma unroll
    for (int jn = 0; jn < 4; jn++) {
        float v = ls[jn];
        v += __shfl_xor(v, 16);
        v += __shfl_xor(v, 32);
        ls[jn] = v;
    }
    if (lane < 16) {
#pragma unroll
        for (int jn = 0; jn < 4; jn++) LS[w][jn * 16 + lane] = ls[jn];
    }

    // sequential k-slice reduction of O^T into wave 0 (scratch = smem)
    float* SC = (float*)smem;  // [64][66] f32
#pragma unroll
    for (int src = 3; src >= 1; --src) {
        __syncthreads();
        if (w == src) {
#pragma unroll
            for (int im = 0; im < 4; im++)
#pragma unroll
                for (int jn = 0; jn < 4; jn++)
#pragma unroll
                    for (int r = 0; r < 4; r++)
                        SC[(im * 16 + g * 4 + r) * 66 + jn * 16 + c] =
                            acc[im][jn][r];
        }
        __syncthreads();
        if (w == src - 1) {
#pragma unroll
            for (int im = 0; im < 4; im++)
#pragma unroll
                for (int jn = 0; jn < 4; jn++)
#pragma unroll
                    for (int r = 0; r < 4; r++)
                        acc[im][jn][r] +=
                            SC[(im * 16 + g * 4 + r) * 66 + jn * 16 + c];
        }
    }
    __syncthreads();

    // wave 0: scale by 1/lsum, write q-major tile for coalesced store
    u16* OT = (u16*)smem;  // [64][72] u16
    if (w == 0) {
#pragma unroll
        for (int jn = 0; jn < 4; jn++) {
            const int q = jn * 16 + c;
            const float inv = 1.f / (LS[0][q] + LS[1][q] + LS[2][q] + LS[3][q]);
#pragma unroll
            for (int im = 0; im < 4; im++)
#pragma unroll
                for (int r = 0; r < 4; r++)
                    OT[q * 72 + im * 16 + g * 4 + r] = f2b(acc[im][jn][r] * inv);
        }
    }
    __syncthreads();

    // coalesced store: thread t -> q = t>>2, d-chunk = (t&3)*16
    {
        const int q = t >> 2, d0 = (t & 3) * 16;
        const int grow = b * 2048 + q0 + q;
        u16* dst = attn + (size_t)grow * 1024 + h * 64 + d0;
        *(s16x8*)dst = *(const s16x8*)&OT[q * 72 + d0];
        *((s16x8*)dst + 1) = *((const s16x8*)&OT[q * 72 + d0] + 1);
    }
}

// =====================================================================
extern "C" void kernel_launch(void* const* d_in, const int* in_sizes, int n_in,
                              void* d_out, int out_size, void* d_ws, size_t ws_size,
                              hipStream_t stream) {
    const float* x = (const float*)d_in[0];
    const float* wq = (const float*)d_in[1];
    const float* bq = (const float*)d_in[2];
    const float* wk = (const float*)d_in[3];
    const float* bk = (const float*)d_in[4];
    const float* wv = (const float*)d_in[5];
    const float* bv = (const float*)d_in[6];
    const float* wo = (const float*)d_in[7];
    const float* bo = (const float*)d_in[8];
    const float* scale1 = (const float*)d_in[9];
    const float* scale2 = (const float*)d_in[10];
    const float* w1 = (const float*)d_in[11];
    const float* b1 = (const float*)d_in[12];
    const float* w2 = (const float*)d_in[13];
    const float* b2 = (const float*)d_in[14];
    float* out = (float*)d_out;

    char* ws = (char*)d_ws;
    size_t off = 0;
    auto alloc = [&](size_t bytes) -> char* {
        char* p = ws + off;
        off += (bytes + 255) & ~(size_t)255;
        return p;
    };
    u16* wqkvT = (u16*)alloc((size_t)3072 * 1024 * 2);   //  6 MB  [ws+0]
    u16* woT   = (u16*)alloc((size_t)1024 * 1024 * 2);   //  2 MB
    u16* w1T   = (u16*)alloc((size_t)4096 * 1024 * 2);   //  8 MB
    u16* w2T   = (u16*)alloc((size_t)1024 * 4096 * 2);   //  8 MB
    float* bqkv = (float*)alloc(3072 * 4);
    u16* xn    = (u16*)alloc((size_t)4096 * 1024 * 2);   //  8 MB
    u16* qkv   = (u16*)alloc((size_t)4096 * 3072 * 2);   // 24 MB
    u16* vT    = (u16*)alloc((size_t)32 * 64 * 2048 * 2);//  8 MB
    u16* attnb = (u16*)alloc((size_t)4096 * 1024 * 2);   //  8 MB
    float* y1  = (float*)alloc((size_t)4096 * 1024 * 4); // 16 MB
    u16* hbuf  = (u16*)alloc((size_t)4096 * 4096 * 2);   // 32 MB

    const size_t SPLIT = (size_t)4096 * 1024;
    Ptr4 po; po.p[0] = (float*)qkv; po.p[1] = (float*)qkv + SPLIT;
    po.p[2] = nullptr; po.p[3] = nullptr;
    Ptr4 pf; pf.p[0] = (float*)xn; pf.p[1] = (float*)xn + SPLIT;
    pf.p[2] = (float*)xn + 2 * SPLIT; pf.p[3] = (float*)wqkvT;

    dim3 blk(256);

    TW6 tw;
    tw.w[0] = wq; tw.o[0] = wqkvT;                          tw.mode[0] = 1;
    tw.w[1] = wk; tw.o[1] = wqkvT + (size_t)1024 * 1024;    tw.mode[1] = 2;
    tw.w[2] = wv; tw.o[2] = wqkvT + (size_t)2048 * 1024;    tw.mode[2] = 0;
    tw.w[3] = wo; tw.o[3] = woT;                            tw.mode[3] = 0;
    tw.w[4] = w1; tw.o[4] = w1T;                            tw.mode[4] = 0;
    tw.w[5] = w2; tw.o[5] = w2T;                            tw.mode[5] = 0;
    tw.bq = bq; tw.bk = bk; tw.bv = bv; tw.bqkv = bqkv;
    prep_weights<<<dim3(128, 32, 6), blk, 0, stream>>>(tw);

    // 1. RMSNorm1
    rmsnorm_kernel<<<4096, blk, 0, stream>>>(x, scale1, xn);
    // 2. QKV GEMM (rotary + log2e pre-folded into weights/bias) -> qkv bf16
    gemm_kernel<0><<<dim3(24, 32), blk, 0, stream>>>(xn, wqkvT, bqkv, nullptr, qkv, 4096, 3072, 1024);
    // 3. per-head V transpose
    transpose_v<<<dim3(64, 2, 32), blk, 0, stream>>>(qkv, vT);
    // 4. flash attention v10 (k-split, 3-buffer counted-vmcnt pipeline)
    attn_kernel<<<dim3(1024), blk, 0, stream>>>(qkv, vT, attnb);
    // 5. O-proj split-K=2
    gemm_splitk<<<dim3(8, 32, 2), blk, 0, stream>>>(attnb, woT, po, 1024, 1024, 512);
    // 6. reduce + bias + resid + RMSNorm2 -> y1 fp32, xn bf16
    reduce_kernel<2, true><<<4096, blk, 0, stream>>>(po, bo, x, scale2, y1, xn);
    // 7. FFN1 + fast exact GELU -> hbuf bf16
    gemm_kernel<2><<<dim3(32, 32), blk, 0, stream>>>(xn, w1T, b1, nullptr, hbuf, 4096, 4096, 1024);
    // 8. FFN2 split-K=4
    gemm_splitk<<<dim3(8, 32, 4), blk, 0, stream>>>(hbuf, w2T, pf, 1024, 4096, 1024);
    // 9. reduce + bias + resid -> out fp32
    reduce_kernel<4, false><<<4096, blk, 0, stream>>>(pf, b2, y1, nullptr, out, nullptr);
}

// Round 6
// 372.343 us; speedup vs baseline: 1.1417x; 1.0034x over previous
//
#include <hip/hip_runtime.h>
#include <hip/hip_bf16.h>
#include <math.h>

typedef unsigned short u16;
typedef short s16x8 __attribute__((ext_vector_type(8)));
typedef short s16x4 __attribute__((ext_vector_type(4)));
typedef __bf16 bf16x8v __attribute__((ext_vector_type(8)));
typedef __bf16 bf16x4v __attribute__((ext_vector_type(4)));
typedef float f32x4 __attribute__((ext_vector_type(4)));
typedef unsigned short u16x4 __attribute__((ext_vector_type(4)));

struct Ptr4 { float* p[4]; };
struct TW6 {
    const float* w[6]; u16* o[6]; int mode[6];
    const float *bq, *bk, *bv; float* bqkv;
};

// ---------- conversions ----------
__device__ __forceinline__ u16 f2b(float f) {
    __hip_bfloat16 h = __float2bfloat16(f);
    return __builtin_bit_cast(u16, h);
}

// ---------- raw v_exp_f32 (2^x) with portable fallback ----------
__device__ __forceinline__ float exp2_fast(float x) {
#if __has_builtin(__builtin_amdgcn_exp2f)
    return __builtin_amdgcn_exp2f(x);
#else
    return exp2f(x);
#endif
}

// ---------- MFMA wrappers ----------
__device__ __forceinline__ f32x4 mfma16(s16x8 a, s16x8 b, f32x4 c) {
    return __builtin_amdgcn_mfma_f32_16x16x32_bf16(
        __builtin_bit_cast(bf16x8v, a), __builtin_bit_cast(bf16x8v, b), c, 0, 0, 0);
}

// 16x16x16 bf16 (K=16) — operands 4 bf16/lane (2 VGPR).
__device__ __forceinline__ f32x4 mfma16k16(s16x4 a, s16x4 b, f32x4 c) {
#if __has_builtin(__builtin_amdgcn_mfma_f32_16x16x16bf16_1k)
    return __builtin_amdgcn_mfma_f32_16x16x16bf16_1k(a, b, c, 0, 0, 0);
#elif __has_builtin(__builtin_amdgcn_mfma_f32_16x16x16_bf16)
    return __builtin_amdgcn_mfma_f32_16x16x16_bf16(
        __builtin_bit_cast(bf16x4v, a), __builtin_bit_cast(bf16x4v, b), c, 0, 0, 0);
#else
    f32x4 d;
    asm volatile("v_mfma_f32_16x16x16_bf16 %0, %1, %2, %3"
                 : "=v"(d)
                 : "v"(a), "v"(b), "v"(c));
    return d;
#endif
}

// ---------- async global->LDS, 16B per lane ----------
__device__ __forceinline__ void gl_lds16(const void* g, void* l) {
    typedef const unsigned int __attribute__((address_space(1))) * gp_t;
    typedef unsigned int __attribute__((address_space(3))) * lp_t;
    __builtin_amdgcn_global_load_lds((gp_t)(unsigned long long)g,
                                     (lp_t)(unsigned int)(unsigned long long)l,
                                     16, 0, 0);
}

// ---------- cheap exact-enough GELU (tanh-form; max dev ~3e-4) ----------
__device__ __forceinline__ float gelu_fast(float v) {
    float u = 1.5957691216f * (v + 0.044715f * v * v * v);
    return v / (1.f + __expf(-u));
}

// Q-side scale: 1/sqrt(64) * log2(e) folded into wq and bq so attention
// softmax can use raw v_exp_f32 (2^x) with no per-element multiply.
#define QSCALE 0.1803368801111244f

// =====================================================================
// Unified weight prep (one launch): grid (128, 32, 6).
//  z 0..3: 1024x1024 transpose+bf16 (x<32 active; z==0,x in [32,44): bias)
//          mode 1 = rotary*QSCALE (wq), 2 = rotary (wk), 0 = plain
//  z 4: w1 [1024,4096] -> w1T[4096,1024]
//  z 5: w2 [4096,1024] -> w2T[1024,4096]
// Rotary is linear: fold column-difference (within 64-wide head) into W.
// =====================================================================
__global__ __launch_bounds__(256) void prep_weights(TW6 io) {
    const int z = blockIdx.z, bx = blockIdx.x, by = blockIdx.y;
    const float* W; u16* Wt; int mode = 0, N_, K_, n0, k0;
    if (z < 4) {
        if (bx >= 32) {
            if (z == 0 && bx < 44 && by == 0) {
                const int i = (bx - 32) * 256 + threadIdx.x;  // 0..3071
                const int d = i & 1023;
                const int dp = (d & ~63) | ((d + 63) & 63);
                float v;
                if (i < 1024) v = QSCALE * (io.bq[d] - io.bq[dp]);
                else if (i < 2048) v = io.bk[d] - io.bk[dp];
                else v = io.bv[d];
                io.bqkv[i] = v;
            }
            return;
        }
        W = io.w[z]; Wt = io.o[z]; mode = io.mode[z];
        N_ = 1024; K_ = 1024; n0 = bx * 32; k0 = by * 32;
    } else if (z == 4) {
        W = io.w[4]; Wt = io.o[4]; N_ = 4096; K_ = 1024; n0 = bx * 32; k0 = by * 32;
    } else {
        W = io.w[5]; Wt = io.o[5]; N_ = 1024; K_ = 4096; n0 = by * 32; k0 = bx * 32;
    }
    __shared__ u16 tile[32][33];
    const int tx = threadIdx.x & 31, ty = threadIdx.x >> 5;
    const int n = n0 + tx;
    const int np = (n & ~63) | ((n + 63) & 63);
    const float s = (mode == 1) ? QSCALE : 1.f;
#pragma unroll
    for (int i = 0; i < 32; i += 8) {
        const size_t r = (size_t)(k0 + ty + i) * N_;
        float v = W[r + n];
        if (mode) v = (v - W[r + np]) * s;
        tile[ty + i][tx] = f2b(v);
    }
    __syncthreads();
#pragma unroll
    for (int i = 0; i < 32; i += 8)
        Wt[(size_t)(n0 + ty + i) * K_ + k0 + tx] = tile[tx][ty + i];
}

// =====================================================================
// V transpose: qkv[b*2048+n][2048+h*64+d] -> vT[(bh)*64+d][n] (per-head)
// =====================================================================
__global__ __launch_bounds__(256) void transpose_v(const u16* __restrict__ qkv,
                                                   u16* __restrict__ vT) {
    __shared__ u16 tile[32][33];
    const int tx = threadIdx.x & 31, ty = threadIdx.x >> 5;
    const int n0 = blockIdx.x * 32, d0 = blockIdx.y * 32, bh = blockIdx.z;
    const int b = bh >> 4, h = bh & 15;
#pragma unroll
    for (int i = 0; i < 32; i += 8)
        tile[ty + i][tx] =
            qkv[(size_t)(b * 2048 + n0 + ty + i) * 3072 + 2048 + h * 64 + d0 + tx];
    __syncthreads();
#pragma unroll
    for (int i = 0; i < 32; i += 8)
        vT[((size_t)bh * 64 + d0 + ty + i) * 2048 + n0 + tx] = tile[tx][ty + i];
}

// =====================================================================
// RMSNorm: fp32 in [rows, 1024] -> bf16 out
// =====================================================================
__global__ __launch_bounds__(256) void rmsnorm_kernel(const float* __restrict__ x,
                                                      const float* __restrict__ scale,
                                                      u16* __restrict__ out) {
    __shared__ float red[4];
    const int t = threadIdx.x, row = blockIdx.x;
    const float4* xr = (const float4*)(x + (size_t)row * 1024);
    float4 v = xr[t];
    float ss = v.x * v.x + v.y * v.y + v.z * v.z + v.w * v.w;
#pragma unroll
    for (int off = 1; off < 64; off <<= 1) ss += __shfl_xor(ss, off);
    if ((t & 63) == 0) red[t >> 6] = ss;
    __syncthreads();
    float tot = red[0] + red[1] + red[2] + red[3];
    float inv = 1.f / (sqrtf(tot * (1.f / 1024.f)) + 1e-8f);
    const float4* sr = (const float4*)scale;
    float4 s = sr[t];
    u16x4 o;
    o[0] = f2b(v.x * inv * s.x);
    o[1] = f2b(v.y * inv * s.y);
    o[2] = f2b(v.z * inv * s.z);
    o[3] = f2b(v.w * inv * s.w);
    ((u16x4*)(out + (size_t)row * 1024))[t] = o;
}

// =====================================================================
// bf16 MFMA GEMM, 128x128 tile, BK=64 (half the barriers of BK=32 for
// short-K GEMMs), 4 waves (2x2 of 64x64), 32 KB LDS.
// 8-chunk XOR swizzle: logical chunk k of row r lives at slot k^(r&7)
// -> b128 fragment reads 2-way (free); staging dest stays lane*16.
// EPI: 0 = bf16(AB+bias); 1 = f32(AB+bias+resid); 2 = bf16(gelu(AB+bias))
// =====================================================================
template <int EPI>
__global__ __launch_bounds__(256) void gemm_kernel(const u16* __restrict__ A,
                                                   const u16* __restrict__ Bt,
                                                   const float* __restrict__ bias,
                                                   const float* __restrict__ resid,
                                                   void* __restrict__ outp,
                                                   int M, int N, int K) {
    __shared__ __align__(16) u16 As[128 * 64];
    __shared__ __align__(16) u16 Bs[128 * 64];
    const int t = threadIdx.x, lane = t & 63;
    const int w = t >> 6, wm = (w >> 1) * 64, wn = (w & 1) * 64;
    const int c = lane & 15, qd = lane >> 4;
    const int n0 = blockIdx.x * 128, m0 = blockIdx.y * 128;

    const int srow = t >> 3;                          // 0..31
    const int sch8 = ((t & 7) ^ (srow & 7)) * 8;      // swizzled source col
    const u16* Ag = A + (size_t)(m0 + srow) * K + sch8;
    const u16* Bg = Bt + (size_t)(n0 + srow) * K + sch8;
    const size_t rstride = (size_t)32 * K;

    f32x4 acc[4][4] = {};
    for (int kt = 0; kt < K; kt += 64) {
        __syncthreads();
#pragma unroll
        for (int g = 0; g < 4; g++) {
            gl_lds16(Ag + g * rstride, &As[t * 8 + g * 2048]);
            gl_lds16(Bg + g * rstride, &Bs[t * 8 + g * 2048]);
        }
        Ag += 64;
        Bg += 64;
        __syncthreads();
#pragma unroll
        for (int s = 0; s < 2; s++) {
            s16x8 a[4], b[4];
#pragma unroll
            for (int im = 0; im < 4; im++)
                a[im] = *(const s16x8*)&As[(wm + im * 16 + c) * 64 +
                                           (((s * 4 + qd) ^ (c & 7)) * 8)];
#pragma unroll
            for (int jn = 0; jn < 4; jn++)
                b[jn] = *(const s16x8*)&Bs[(wn + jn * 16 + c) * 64 +
                                           (((s * 4 + qd) ^ (c & 7)) * 8)];
#pragma unroll
            for (int im = 0; im < 4; im++)
#pragma unroll
                for (int jn = 0; jn < 4; jn++)
                    acc[im][jn] = mfma16(a[im], b[jn], acc[im][jn]);
        }
    }

#pragma unroll
    for (int im = 0; im < 4; im++) {
#pragma unroll
        for (int jn = 0; jn < 4; jn++) {
            const int colg = n0 + wn + jn * 16 + c;
            const float bv = bias[colg];
#pragma unroll
            for (int r = 0; r < 4; r++) {
                const int rowg = m0 + wm + im * 16 + qd * 4 + r;
                const size_t off = (size_t)rowg * N + colg;
                float v = acc[im][jn][r] + bv;
                if (EPI == 0) {
                    ((u16*)outp)[off] = f2b(v);
                } else if (EPI == 1) {
                    ((float*)outp)[off] = v + resid[off];
                } else {
                    ((u16*)outp)[off] = f2b(gelu_fast(v));
                }
            }
        }
    }
}

// =====================================================================
// Split-K GEMM, BK=64 (same swizzle): blockIdx.z = split; fp32 partials.
// =====================================================================
__global__ __launch_bounds__(256) void gemm_splitk(const u16* __restrict__ A,
                                                   const u16* __restrict__ Bt,
                                                   Ptr4 parts,
                                                   int N, int Ktot, int Kc) {
    __shared__ __align__(16) u16 As[128 * 64];
    __shared__ __align__(16) u16 Bs[128 * 64];
    const int t = threadIdx.x, lane = t & 63;
    const int w = t >> 6, wm = (w >> 1) * 64, wn = (w & 1) * 64;
    const int c = lane & 15, qd = lane >> 4;
    const int n0 = blockIdx.x * 128, m0 = blockIdx.y * 128;
    const int z = blockIdx.z;
    float* out = parts.p[z];

    const int srow = t >> 3;
    const int sch8 = ((t & 7) ^ (srow & 7)) * 8;
    const u16* Ag = A + (size_t)(m0 + srow) * Ktot + z * Kc + sch8;
    const u16* Bg = Bt + (size_t)(n0 + srow) * Ktot + z * Kc + sch8;
    const size_t rstride = (size_t)32 * Ktot;

    f32x4 acc[4][4] = {};
    for (int kt = 0; kt < Kc; kt += 64) {
        __syncthreads();
#pragma unroll
        for (int g = 0; g < 4; g++) {
            gl_lds16(Ag + g * rstride, &As[t * 8 + g * 2048]);
            gl_lds16(Bg + g * rstride, &Bs[t * 8 + g * 2048]);
        }
        Ag += 64;
        Bg += 64;
        __syncthreads();
#pragma unroll
        for (int s = 0; s < 2; s++) {
            s16x8 a[4], b[4];
#pragma unroll
            for (int im = 0; im < 4; im++)
                a[im] = *(const s16x8*)&As[(wm + im * 16 + c) * 64 +
                                           (((s * 4 + qd) ^ (c & 7)) * 8)];
#pragma unroll
            for (int jn = 0; jn < 4; jn++)
                b[jn] = *(const s16x8*)&Bs[(wn + jn * 16 + c) * 64 +
                                           (((s * 4 + qd) ^ (c & 7)) * 8)];
#pragma unroll
            for (int im = 0; im < 4; im++)
#pragma unroll
                for (int jn = 0; jn < 4; jn++)
                    acc[im][jn] = mfma16(a[im], b[jn], acc[im][jn]);
        }
    }

#pragma unroll
    for (int im = 0; im < 4; im++)
#pragma unroll
        for (int jn = 0; jn < 4; jn++) {
            const int colg = n0 + wn + jn * 16 + c;
#pragma unroll
            for (int r = 0; r < 4; r++) {
                const int rowg = m0 + wm + im * 16 + qd * 4 + r;
                out[(size_t)rowg * N + colg] = acc[im][jn][r];
            }
        }
}

// =====================================================================
// Split-K reduce. One block per row (1024 cols, float4/thread).
// =====================================================================
template <int S, bool NORM>
__global__ __launch_bounds__(256) void reduce_kernel(Ptr4 parts,
                                                     const float* __restrict__ bias,
                                                     const float* __restrict__ resid,
                                                     const float* __restrict__ scale,
                                                     float* __restrict__ yout,
                                                     u16* __restrict__ xnout) {
    __shared__ float red[4];
    const int t = threadIdx.x, row = blockIdx.x;
    const size_t base = (size_t)row * 1024;
    float4 v = ((const float4*)(resid + base))[t];
    float4 bv = ((const float4*)bias)[t];
    v.x += bv.x; v.y += bv.y; v.z += bv.z; v.w += bv.w;
#pragma unroll
    for (int s = 0; s < S; s++) {
        float4 pv = ((const float4*)(parts.p[s] + base))[t];
        v.x += pv.x; v.y += pv.y; v.z += pv.z; v.w += pv.w;
    }
    ((float4*)(yout + base))[t] = v;
    if (NORM) {
        float ss = v.x * v.x + v.y * v.y + v.z * v.z + v.w * v.w;
#pragma unroll
        for (int off = 1; off < 64; off <<= 1) ss += __shfl_xor(ss, off);
        if ((t & 63) == 0) red[t >> 6] = ss;
        __syncthreads();
        float tot = red[0] + red[1] + red[2] + red[3];
        float inv = 1.f / (sqrtf(tot * (1.f / 1024.f)) + 1e-8f);
        float4 s = ((const float4*)scale)[t];
        u16x4 o;
        o[0] = f2b(v.x * inv * s.x);
        o[1] = f2b(v.y * inv * s.y);
        o[2] = f2b(v.z * inv * s.z);
        o[3] = f2b(v.w * inv * s.w);
        ((u16x4*)(xnout + base))[t] = o;
    }
}

// =====================================================================
// Flash attention v11: WAVE-PRIVATE staging, ZERO barriers in main loop.
// k-split: wave w consumes only K rows [16w,16w+16) and V k-cols
// [16w,16w+16) of each 64-KV tile -> each wave stages its OWN 2KB
// K-slice + 2KB V-slice (4 coalesced gl_lds16/lane, disjoint across
// waves, same total traffic). No cross-wave LDS deps => no s_barrier
// for all 32 iterations; per-wave counted s_waitcnt vmcnt(8) only
// (3-buffer rotation, depth-3 prefetch, never drained). Waves drift
// freely -> MFMA/VALU/trans mix across 12 waves/CU.
//  Hazards: stage(it+3) overwrites the buffer read at iter it, but the
//  ds_reads were retired before the PV MFMAs issued (compiler lgkmcnt
//  waits) and gl_lds follows in program order (sched_barrier pins).
//  sched_barrier(0) after each inline waitcnt (rule 18).
// K-slice keeps XOR source-swizzle (2-way b128 reads, free); V-slice
// [64][16] b64 reads at the 4-way inherent floor. Epilogue unchanged.
// =====================================================================
__global__ __launch_bounds__(256, 3) void attn_kernel(const u16* __restrict__ qkv,
                                                      const u16* __restrict__ vT,
                                                      u16* __restrict__ attn) {
    // 4 waves x 3 buffers x 4KB = 48 KB; epilogue reuses slab as
    // SC f32[64][66] (16.9 KB) and OT u16[64][72] (9.2 KB).
    __shared__ __align__(16) char smem[49152];
    __shared__ float LS[4][64];
    u16* SM = (u16*)smem;

    const int t = threadIdx.x, lane = t & 63, w = t >> 6;
    const int c = lane & 15, g = lane >> 4;

    // XCD-grouped bijective swizzle: 1024 blocks, 8 XCDs, 128 blocks/XCD.
    const int id = blockIdx.x;
    const int logical = (id & 7) * 128 + (id >> 3);
    const int bh = logical >> 5, qb = logical & 31;
    const int b = bh >> 4, h = bh & 15;
    const int q0 = qb * 64;
    const size_t rowbase = (size_t)b * 2048;

    const u16* kg = qkv + rowbase * 3072 + 1024 + h * 64;
    const u16* vg = vT + (size_t)bh * 64 * 2048;

    u16* WS = SM + w * 6144;  // wave-private slab (3 x 2048 u16)

    // staging lane decomposition
    const int kr = lane >> 3, ks8 = lane & 7;           // K: row 0..7, chunk
    const int ksw = (ks8 ^ (kr & 7)) * 8;               // swizzled src chunk
    const int vr = lane >> 1, vh = (lane & 1) * 8;      // V: d-row, half

    // stage KV-tile `it`'s wave-slice into wave-private buffer bi.
    auto stage = [&](int it, int bi) {
        u16* B = WS + bi * 2048;
        const u16* kq = kg + (size_t)(it * 64 + w * 16) * 3072;
        const u16* vq = vg + it * 64 + w * 16;
        gl_lds16(kq + (size_t)kr * 3072 + ksw,       &B[lane * 8]);
        gl_lds16(kq + (size_t)(kr + 8) * 3072 + ksw, &B[512 + lane * 8]);
        gl_lds16(vq + (size_t)vr * 2048 + vh,        &B[1024 + lane * 8]);
        gl_lds16(vq + (size_t)(vr + 32) * 2048 + vh, &B[1536 + lane * 8]);
    };

    // Q B-fragments hoisted: qf[jn][ks] covers all 64 q rows of the block.
    s16x8 qf[4][2];
    {
        const u16* qg = qkv + (rowbase + q0) * 3072 + h * 64;
#pragma unroll
        for (int jn = 0; jn < 4; jn++)
#pragma unroll
            for (int ks = 0; ks < 2; ks++)
                qf[jn][ks] = *(const s16x8*)&qg[(size_t)(jn * 16 + c) * 3072 +
                                                ks * 32 + g * 8];
    }

    stage(0, 0);
    stage(1, 1);
    stage(2, 2);

    f32x4 acc[4][4] = {};   // O^T partial: [im: d-tile][jn: q-tile]
    float ls[4] = {};       // lane-local lsum partial per q-tile

    int bi = 0;
    for (int it = 0; it < 32; it++) {
        // counted per-wave wait: stage(it) landed; stage(it+1..2) in flight.
        if (it < 30)
            asm volatile("s_waitcnt vmcnt(8)" ::: "memory");
        else if (it == 30)
            asm volatile("s_waitcnt vmcnt(4)" ::: "memory");
        else
            asm volatile("s_waitcnt vmcnt(0)" ::: "memory");
        __builtin_amdgcn_sched_barrier(0);

        const u16* Kb = WS + bi * 2048;
        const u16* Vb = Kb + 1024;

        // K A-frags: slice rows = c, d = ks*32 + g*8 (XOR-swizzled chunks)
        s16x8 kf[2];
#pragma unroll
        for (int ks = 0; ks < 2; ks++)
            kf[ks] = *(const s16x8*)&Kb[c * 64 + (((ks * 4 + g) ^ (c & 7)) * 8)];
        // V^T A-frags: d-row = im*16+c, k-col = g*4..+3 (b64 reads)
        s16x4 vf[4];
#pragma unroll
        for (int im = 0; im < 4; im++)
            vf[im] = *(const s16x4*)&Vb[(im * 16 + c) * 16 + g * 4];

        // swapped QK^T: sc[jn] lane: q = jn*16+c, k = w*16 + g*4 + r
        f32x4 sc[4] = {};
        __builtin_amdgcn_s_setprio(1);
#pragma unroll
        for (int ks = 0; ks < 2; ks++)
#pragma unroll
            for (int jn = 0; jn < 4; jn++)
                sc[jn] = mfma16(kf[ks], qf[jn][ks], sc[jn]);
        __builtin_amdgcn_s_setprio(0);

        // softmax (no-max, exp2) + pack into PV B-fragments
        s16x4 pb[4];
#pragma unroll
        for (int jn = 0; jn < 4; jn++) {
            float p0 = exp2_fast(sc[jn][0]);
            float p1 = exp2_fast(sc[jn][1]);
            float p2 = exp2_fast(sc[jn][2]);
            float p3 = exp2_fast(sc[jn][3]);
            ls[jn] += (p0 + p1) + (p2 + p3);
            pb[jn][0] = f2b(p0); pb[jn][1] = f2b(p1);
            pb[jn][2] = f2b(p2); pb[jn][3] = f2b(p3);
        }

        // PV: O^T[d][q] += V^T(d x k16) * P^T(k16 x q)
        __builtin_amdgcn_s_setprio(1);
#pragma unroll
        for (int im = 0; im < 4; im++)
#pragma unroll
            for (int jn = 0; jn < 4; jn++)
                acc[im][jn] = mfma16k16(vf[im], pb[jn], acc[im][jn]);
        __builtin_amdgcn_s_setprio(0);

        // refill this buffer with tile it+3 (reads above already retired)
        __builtin_amdgcn_sched_barrier(0);
        if (it + 3 < 32) stage(it + 3, bi);

        bi = (bi == 2) ? 0 : bi + 1;
    }

    // lsum: reduce across lane groups (k within slice), publish per wave
#pragma unroll
    for (int jn = 0; jn < 4; jn++) {
        float v = ls[jn];
        v += __shfl_xor(v, 16);
        v += __shfl_xor(v, 32);
        ls[jn] = v;
    }
    if (lane < 16) {
#pragma unroll
        for (int jn = 0; jn < 4; jn++) LS[w][jn * 16 + lane] = ls[jn];
    }

    // sequential k-slice reduction of O^T into wave 0 (scratch = smem)
    float* SC = (float*)smem;  // [64][66] f32
#pragma unroll
    for (int src = 3; src >= 1; --src) {
        __syncthreads();
        if (w == src) {
#pragma unroll
            for (int im = 0; im < 4; im++)
#pragma unroll
                for (int jn = 0; jn < 4; jn++)
#pragma unroll
                    for (int r = 0; r < 4; r++)
                        SC[(im * 16 + g * 4 + r) * 66 + jn * 16 + c] =
                            acc[im][jn][r];
        }
        __syncthreads();
        if (w == src - 1) {
#pragma unroll
            for (int im = 0; im < 4; im++)
#pragma unroll
                for (int jn = 0; jn < 4; jn++)
#pragma unroll
                    for (int r = 0; r < 4; r++)
                        acc[im][jn][r] +=
                            SC[(im * 16 + g * 4 + r) * 66 + jn * 16 + c];
        }
    }
    __syncthreads();

    // wave 0: scale by 1/lsum, write q-major tile for coalesced store
    u16* OT = (u16*)smem;  // [64][72] u16
    if (w == 0) {
#pragma unroll
        for (int jn = 0; jn < 4; jn++) {
            const int q = jn * 16 + c;
            const float inv = 1.f / (LS[0][q] + LS[1][q] + LS[2][q] + LS[3][q]);
#pragma unroll
            for (int im = 0; im < 4; im++)
#pragma unroll
                for (int r = 0; r < 4; r++)
                    OT[q * 72 + im * 16 + g * 4 + r] = f2b(acc[im][jn][r] * inv);
        }
    }
    __syncthreads();

    // coalesced store: thread t -> q = t>>2, d-chunk = (t&3)*16
    {
        const int q = t >> 2, d0 = (t & 3) * 16;
        const int grow = b * 2048 + q0 + q;
        u16* dst = attn + (size_t)grow * 1024 + h * 64 + d0;
        *(s16x8*)dst = *(const s16x8*)&OT[q * 72 + d0];
        *((s16x8*)dst + 1) = *((const s16x8*)&OT[q * 72 + d0] + 1);
    }
}

// =====================================================================
extern "C" void kernel_launch(void* const* d_in, const int* in_sizes, int n_in,
                              void* d_out, int out_size, void* d_ws, size_t ws_size,
                              hipStream_t stream) {
    const float* x = (const float*)d_in[0];
    const float* wq = (const float*)d_in[1];
    const float* bq = (const float*)d_in[2];
    const float* wk = (const float*)d_in[3];
    const float* bk = (const float*)d_in[4];
    const float* wv = (const float*)d_in[5];
    const float* bv = (const float*)d_in[6];
    const float* wo = (const float*)d_in[7];
    const float* bo = (const float*)d_in[8];
    const float* scale1 = (const float*)d_in[9];
    const float* scale2 = (const float*)d_in[10];
    const float* w1 = (const float*)d_in[11];
    const float* b1 = (const float*)d_in[12];
    const float* w2 = (const float*)d_in[13];
    const float* b2 = (const float*)d_in[14];
    float* out = (float*)d_out;

    char* ws = (char*)d_ws;
    size_t off = 0;
    auto alloc = [&](size_t bytes) -> char* {
        char* p = ws + off;
        off += (bytes + 255) & ~(size_t)255;
        return p;
    };
    u16* wqkvT = (u16*)alloc((size_t)3072 * 1024 * 2);   //  6 MB  [ws+0]
    u16* woT   = (u16*)alloc((size_t)1024 * 1024 * 2);   //  2 MB
    u16* w1T   = (u16*)alloc((size_t)4096 * 1024 * 2);   //  8 MB
    u16* w2T   = (u16*)alloc((size_t)1024 * 4096 * 2);   //  8 MB
    float* bqkv = (float*)alloc(3072 * 4);
    u16* xn    = (u16*)alloc((size_t)4096 * 1024 * 2);   //  8 MB
    u16* qkv   = (u16*)alloc((size_t)4096 * 3072 * 2);   // 24 MB
    u16* vT    = (u16*)alloc((size_t)32 * 64 * 2048 * 2);//  8 MB
    u16* attnb = (u16*)alloc((size_t)4096 * 1024 * 2);   //  8 MB
    float* y1  = (float*)alloc((size_t)4096 * 1024 * 4); // 16 MB
    u16* hbuf  = (u16*)alloc((size_t)4096 * 4096 * 2);   // 32 MB

    const size_t SPLIT = (size_t)4096 * 1024;
    Ptr4 po; po.p[0] = (float*)qkv; po.p[1] = (float*)qkv + SPLIT;
    po.p[2] = nullptr; po.p[3] = nullptr;
    Ptr4 pf; pf.p[0] = (float*)xn; pf.p[1] = (float*)xn + SPLIT;
    pf.p[2] = (float*)xn + 2 * SPLIT; pf.p[3] = (float*)wqkvT;

    dim3 blk(256);

    TW6 tw;
    tw.w[0] = wq; tw.o[0] = wqkvT;                          tw.mode[0] = 1;
    tw.w[1] = wk; tw.o[1] = wqkvT + (size_t)1024 * 1024;    tw.mode[1] = 2;
    tw.w[2] = wv; tw.o[2] = wqkvT + (size_t)2048 * 1024;    tw.mode[2] = 0;
    tw.w[3] = wo; tw.o[3] = woT;                            tw.mode[3] = 0;
    tw.w[4] = w1; tw.o[4] = w1T;                            tw.mode[4] = 0;
    tw.w[5] = w2; tw.o[5] = w2T;                            tw.mode[5] = 0;
    tw.bq = bq; tw.bk = bk; tw.bv = bv; tw.bqkv = bqkv;
    prep_weights<<<dim3(128, 32, 6), blk, 0, stream>>>(tw);

    // 1. RMSNorm1
    rmsnorm_kernel<<<4096, blk, 0, stream>>>(x, scale1, xn);
    // 2. QKV GEMM (rotary + log2e pre-folded into weights/bias) -> qkv bf16
    gemm_kernel<0><<<dim3(24, 32), blk, 0, stream>>>(xn, wqkvT, bqkv, nullptr, qkv, 4096, 3072, 1024);
    // 3. per-head V transpose
    transpose_v<<<dim3(64, 2, 32), blk, 0, stream>>>(qkv, vT);
    // 4. flash attention v11 (wave-private staging, barrier-free loop)
    attn_kernel<<<dim3(1024), blk, 0, stream>>>(qkv, vT, attnb);
    // 5. O-proj split-K=2
    gemm_splitk<<<dim3(8, 32, 2), blk, 0, stream>>>(attnb, woT, po, 1024, 1024, 512);
    // 6. reduce + bias + resid + RMSNorm2 -> y1 fp32, xn bf16
    reduce_kernel<2, true><<<4096, blk, 0, stream>>>(po, bo, x, scale2, y1, xn);
    // 7. FFN1 + fast exact GELU -> hbuf bf16
    gemm_kernel<2><<<dim3(32, 32), blk, 0, stream>>>(xn, w1T, b1, nullptr, hbuf, 4096, 4096, 1024);
    // 8. FFN2 split-K=4
    gemm_splitk<<<dim3(8, 32, 4), blk, 0, stream>>>(hbuf, w2T, pf, 1024, 4096, 1024);
    // 9. reduce + bias + resid -> out fp32
    reduce_kernel<4, false><<<4096, blk, 0, stream>>>(pf, b2, y1, nullptr, out, nullptr);
}

// Round 7
// 366.173 us; speedup vs baseline: 1.1610x; 1.0168x over previous
//
#include <hip/hip_runtime.h>
#include <hip/hip_bf16.h>
#include <math.h>

typedef unsigned short u16;
typedef short s16x8 __attribute__((ext_vector_type(8)));
typedef short s16x4 __attribute__((ext_vector_type(4)));
typedef __bf16 bf16x8v __attribute__((ext_vector_type(8)));
typedef float f32x4 __attribute__((ext_vector_type(4)));
typedef unsigned short u16x4 __attribute__((ext_vector_type(4)));

struct Ptr4 { float* p[4]; };
struct TW6 {
    const float* w[6]; u16* o[6]; int mode[6];
    const float *bq, *bk, *bv; float* bqkv;
};

// ---------- conversions ----------
__device__ __forceinline__ u16 f2b(float f) {
    __hip_bfloat16 h = __float2bfloat16(f);
    return __builtin_bit_cast(u16, h);
}

// ---------- raw v_exp_f32 (2^x) with portable fallback ----------
__device__ __forceinline__ float exp2_fast(float x) {
#if __has_builtin(__builtin_amdgcn_exp2f)
    return __builtin_amdgcn_exp2f(x);
#else
    return exp2f(x);
#endif
}

// ---------- MFMA wrapper (gfx950: v8bf16 operands) ----------
__device__ __forceinline__ f32x4 mfma16(s16x8 a, s16x8 b, f32x4 c) {
    return __builtin_amdgcn_mfma_f32_16x16x32_bf16(
        __builtin_bit_cast(bf16x8v, a), __builtin_bit_cast(bf16x8v, b), c, 0, 0, 0);
}

// ---------- async global->LDS, 16B per lane ----------
__device__ __forceinline__ void gl_lds16(const void* g, void* l) {
    typedef const unsigned int __attribute__((address_space(1))) * gp_t;
    typedef unsigned int __attribute__((address_space(3))) * lp_t;
    __builtin_amdgcn_global_load_lds((gp_t)(unsigned long long)g,
                                     (lp_t)(unsigned int)(unsigned long long)l,
                                     16, 0, 0);
}

// ---------- cheap exact-enough GELU (tanh-form; max dev ~3e-4) ----------
__device__ __forceinline__ float gelu_fast(float v) {
    float u = 1.5957691216f * (v + 0.044715f * v * v * v);
    return v / (1.f + __expf(-u));
}

// Q-side scale: 1/sqrt(64) * log2(e) folded into wq and bq so attention
// softmax can use raw v_exp_f32 (2^x) with no per-element multiply.
#define QSCALE 0.1803368801111244f

// =====================================================================
// Unified weight prep (one launch): grid (128, 32, 6).
//  z 0..3: 1024x1024 transpose+bf16 (x<32 active; z==0,x in [32,44): bias)
//          mode 1 = rotary*QSCALE (wq), 2 = rotary (wk), 0 = plain
//  z 4: w1 [1024,4096] -> w1T[4096,1024]
//  z 5: w2 [4096,1024] -> w2T[1024,4096]
// Rotary is linear: fold column-difference (within 64-wide head) into W.
// =====================================================================
__global__ __launch_bounds__(256) void prep_weights(TW6 io) {
    const int z = blockIdx.z, bx = blockIdx.x, by = blockIdx.y;
    const float* W; u16* Wt; int mode = 0, N_, K_, n0, k0;
    if (z < 4) {
        if (bx >= 32) {
            if (z == 0 && bx < 44 && by == 0) {
                const int i = (bx - 32) * 256 + threadIdx.x;  // 0..3071
                const int d = i & 1023;
                const int dp = (d & ~63) | ((d + 63) & 63);
                float v;
                if (i < 1024) v = QSCALE * (io.bq[d] - io.bq[dp]);
                else if (i < 2048) v = io.bk[d] - io.bk[dp];
                else v = io.bv[d];
                io.bqkv[i] = v;
            }
            return;
        }
        W = io.w[z]; Wt = io.o[z]; mode = io.mode[z];
        N_ = 1024; K_ = 1024; n0 = bx * 32; k0 = by * 32;
    } else if (z == 4) {
        W = io.w[4]; Wt = io.o[4]; N_ = 4096; K_ = 1024; n0 = bx * 32; k0 = by * 32;
    } else {
        W = io.w[5]; Wt = io.o[5]; N_ = 1024; K_ = 4096; n0 = by * 32; k0 = bx * 32;
    }
    __shared__ u16 tile[32][33];
    const int tx = threadIdx.x & 31, ty = threadIdx.x >> 5;
    const int n = n0 + tx;
    const int np = (n & ~63) | ((n + 63) & 63);
    const float s = (mode == 1) ? QSCALE : 1.f;
#pragma unroll
    for (int i = 0; i < 32; i += 8) {
        const size_t r = (size_t)(k0 + ty + i) * N_;
        float v = W[r + n];
        if (mode) v = (v - W[r + np]) * s;
        tile[ty + i][tx] = f2b(v);
    }
    __syncthreads();
#pragma unroll
    for (int i = 0; i < 32; i += 8)
        Wt[(size_t)(n0 + ty + i) * K_ + k0 + tx] = tile[tx][ty + i];
}

// =====================================================================
// V transpose: qkv[b*2048+n][2048+h*64+d] -> vT[(bh)*64+d][n] (per-head)
// =====================================================================
__global__ __launch_bounds__(256) void transpose_v(const u16* __restrict__ qkv,
                                                   u16* __restrict__ vT) {
    __shared__ u16 tile[32][33];
    const int tx = threadIdx.x & 31, ty = threadIdx.x >> 5;
    const int n0 = blockIdx.x * 32, d0 = blockIdx.y * 32, bh = blockIdx.z;
    const int b = bh >> 4, h = bh & 15;
#pragma unroll
    for (int i = 0; i < 32; i += 8)
        tile[ty + i][tx] =
            qkv[(size_t)(b * 2048 + n0 + ty + i) * 3072 + 2048 + h * 64 + d0 + tx];
    __syncthreads();
#pragma unroll
    for (int i = 0; i < 32; i += 8)
        vT[((size_t)bh * 64 + d0 + ty + i) * 2048 + n0 + tx] = tile[tx][ty + i];
}

// =====================================================================
// RMSNorm: fp32 in [rows, 1024] -> bf16 out
// =====================================================================
__global__ __launch_bounds__(256) void rmsnorm_kernel(const float* __restrict__ x,
                                                      const float* __restrict__ scale,
                                                      u16* __restrict__ out) {
    __shared__ float red[4];
    const int t = threadIdx.x, row = blockIdx.x;
    const float4* xr = (const float4*)(x + (size_t)row * 1024);
    float4 v = xr[t];
    float ss = v.x * v.x + v.y * v.y + v.z * v.z + v.w * v.w;
#pragma unroll
    for (int off = 1; off < 64; off <<= 1) ss += __shfl_xor(ss, off);
    if ((t & 63) == 0) red[t >> 6] = ss;
    __syncthreads();
    float tot = red[0] + red[1] + red[2] + red[3];
    float inv = 1.f / (sqrtf(tot * (1.f / 1024.f)) + 1e-8f);
    const float4* sr = (const float4*)scale;
    float4 s = sr[t];
    u16x4 o;
    o[0] = f2b(v.x * inv * s.x);
    o[1] = f2b(v.y * inv * s.y);
    o[2] = f2b(v.z * inv * s.z);
    o[3] = f2b(v.w * inv * s.w);
    ((u16x4*)(out + (size_t)row * 1024))[t] = o;
}

// =====================================================================
// bf16 MFMA GEMM, 128x128 tile, BK=64 (half the barriers of BK=32 for
// short-K GEMMs), 4 waves (2x2 of 64x64), 32 KB LDS.
// 8-chunk XOR swizzle: logical chunk k of row r lives at slot k^(r&7)
// -> b128 fragment reads 2-way (free); staging dest stays lane*16.
// EPI: 0 = bf16(AB+bias); 1 = f32(AB+bias+resid); 2 = bf16(gelu(AB+bias))
// =====================================================================
template <int EPI>
__global__ __launch_bounds__(256) void gemm_kernel(const u16* __restrict__ A,
                                                   const u16* __restrict__ Bt,
                                                   const float* __restrict__ bias,
                                                   const float* __restrict__ resid,
                                                   void* __restrict__ outp,
                                                   int M, int N, int K) {
    __shared__ __align__(16) u16 As[128 * 64];
    __shared__ __align__(16) u16 Bs[128 * 64];
    const int t = threadIdx.x, lane = t & 63;
    const int w = t >> 6, wm = (w >> 1) * 64, wn = (w & 1) * 64;
    const int c = lane & 15, qd = lane >> 4;
    const int n0 = blockIdx.x * 128, m0 = blockIdx.y * 128;

    const int srow = t >> 3;                          // 0..31
    const int sch8 = ((t & 7) ^ (srow & 7)) * 8;      // swizzled source col
    const u16* Ag = A + (size_t)(m0 + srow) * K + sch8;
    const u16* Bg = Bt + (size_t)(n0 + srow) * K + sch8;
    const size_t rstride = (size_t)32 * K;

    f32x4 acc[4][4] = {};
    for (int kt = 0; kt < K; kt += 64) {
        __syncthreads();
#pragma unroll
        for (int g = 0; g < 4; g++) {
            gl_lds16(Ag + g * rstride, &As[t * 8 + g * 2048]);
            gl_lds16(Bg + g * rstride, &Bs[t * 8 + g * 2048]);
        }
        Ag += 64;
        Bg += 64;
        __syncthreads();
#pragma unroll
        for (int s = 0; s < 2; s++) {
            s16x8 a[4], b[4];
#pragma unroll
            for (int im = 0; im < 4; im++)
                a[im] = *(const s16x8*)&As[(wm + im * 16 + c) * 64 +
                                           (((s * 4 + qd) ^ (c & 7)) * 8)];
#pragma unroll
            for (int jn = 0; jn < 4; jn++)
                b[jn] = *(const s16x8*)&Bs[(wn + jn * 16 + c) * 64 +
                                           (((s * 4 + qd) ^ (c & 7)) * 8)];
#pragma unroll
            for (int im = 0; im < 4; im++)
#pragma unroll
                for (int jn = 0; jn < 4; jn++)
                    acc[im][jn] = mfma16(a[im], b[jn], acc[im][jn]);
        }
    }

#pragma unroll
    for (int im = 0; im < 4; im++) {
#pragma unroll
        for (int jn = 0; jn < 4; jn++) {
            const int colg = n0 + wn + jn * 16 + c;
            const float bv = bias[colg];
#pragma unroll
            for (int r = 0; r < 4; r++) {
                const int rowg = m0 + wm + im * 16 + qd * 4 + r;
                const size_t off = (size_t)rowg * N + colg;
                float v = acc[im][jn][r] + bv;
                if (EPI == 0) {
                    ((u16*)outp)[off] = f2b(v);
                } else if (EPI == 1) {
                    ((float*)outp)[off] = v + resid[off];
                } else {
                    ((u16*)outp)[off] = f2b(gelu_fast(v));
                }
            }
        }
    }
}

// =====================================================================
// Split-K GEMM, BK=64 (same swizzle): blockIdx.z = split; fp32 partials.
// =====================================================================
__global__ __launch_bounds__(256) void gemm_splitk(const u16* __restrict__ A,
                                                   const u16* __restrict__ Bt,
                                                   Ptr4 parts,
                                                   int N, int Ktot, int Kc) {
    __shared__ __align__(16) u16 As[128 * 64];
    __shared__ __align__(16) u16 Bs[128 * 64];
    const int t = threadIdx.x, lane = t & 63;
    const int w = t >> 6, wm = (w >> 1) * 64, wn = (w & 1) * 64;
    const int c = lane & 15, qd = lane >> 4;
    const int n0 = blockIdx.x * 128, m0 = blockIdx.y * 128;
    const int z = blockIdx.z;
    float* out = parts.p[z];

    const int srow = t >> 3;
    const int sch8 = ((t & 7) ^ (srow & 7)) * 8;
    const u16* Ag = A + (size_t)(m0 + srow) * Ktot + z * Kc + sch8;
    const u16* Bg = Bt + (size_t)(n0 + srow) * Ktot + z * Kc + sch8;
    const size_t rstride = (size_t)32 * Ktot;

    f32x4 acc[4][4] = {};
    for (int kt = 0; kt < Kc; kt += 64) {
        __syncthreads();
#pragma unroll
        for (int g = 0; g < 4; g++) {
            gl_lds16(Ag + g * rstride, &As[t * 8 + g * 2048]);
            gl_lds16(Bg + g * rstride, &Bs[t * 8 + g * 2048]);
        }
        Ag += 64;
        Bg += 64;
        __syncthreads();
#pragma unroll
        for (int s = 0; s < 2; s++) {
            s16x8 a[4], b[4];
#pragma unroll
            for (int im = 0; im < 4; im++)
                a[im] = *(const s16x8*)&As[(wm + im * 16 + c) * 64 +
                                           (((s * 4 + qd) ^ (c & 7)) * 8)];
#pragma unroll
            for (int jn = 0; jn < 4; jn++)
                b[jn] = *(const s16x8*)&Bs[(wn + jn * 16 + c) * 64 +
                                           (((s * 4 + qd) ^ (c & 7)) * 8)];
#pragma unroll
            for (int im = 0; im < 4; im++)
#pragma unroll
                for (int jn = 0; jn < 4; jn++)
                    acc[im][jn] = mfma16(a[im], b[jn], acc[im][jn]);
        }
    }

#pragma unroll
    for (int im = 0; im < 4; im++)
#pragma unroll
        for (int jn = 0; jn < 4; jn++) {
            const int colg = n0 + wn + jn * 16 + c;
#pragma unroll
            for (int r = 0; r < 4; r++) {
                const int rowg = m0 + wm + im * 16 + qd * 4 + r;
                out[(size_t)rowg * N + colg] = acc[im][jn][r];
            }
        }
}

// =====================================================================
// Split-K reduce. One block per row (1024 cols, float4/thread).
// =====================================================================
template <int S, bool NORM>
__global__ __launch_bounds__(256) void reduce_kernel(Ptr4 parts,
                                                     const float* __restrict__ bias,
                                                     const float* __restrict__ resid,
                                                     const float* __restrict__ scale,
                                                     float* __restrict__ yout,
                                                     u16* __restrict__ xnout) {
    __shared__ float red[4];
    const int t = threadIdx.x, row = blockIdx.x;
    const size_t base = (size_t)row * 1024;
    float4 v = ((const float4*)(resid + base))[t];
    float4 bv = ((const float4*)bias)[t];
    v.x += bv.x; v.y += bv.y; v.z += bv.z; v.w += bv.w;
#pragma unroll
    for (int s = 0; s < S; s++) {
        float4 pv = ((const float4*)(parts.p[s] + base))[t];
        v.x += pv.x; v.y += pv.y; v.z += pv.z; v.w += pv.w;
    }
    ((float4*)(yout + base))[t] = v;
    if (NORM) {
        float ss = v.x * v.x + v.y * v.y + v.z * v.z + v.w * v.w;
#pragma unroll
        for (int off = 1; off < 64; off <<= 1) ss += __shfl_xor(ss, off);
        if ((t & 63) == 0) red[t >> 6] = ss;
        __syncthreads();
        float tot = red[0] + red[1] + red[2] + red[3];
        float inv = 1.f / (sqrtf(tot * (1.f / 1024.f)) + 1e-8f);
        float4 s = ((const float4*)scale)[t];
        u16x4 o;
        o[0] = f2b(v.x * inv * s.x);
        o[1] = f2b(v.y * inv * s.y);
        o[2] = f2b(v.z * inv * s.z);
        o[3] = f2b(v.w * inv * s.w);
        ((u16x4*)(xnout + base))[t] = o;
    }
}

// =====================================================================
// Flash attention v12: 2-tile fusion + K=32 PV.
// k-split (wave w owns k rows [16w,16w+16) of each 64-KV tile), wave-
// private staging, zero barriers in main loop (from v11). NEW: process
// 2 KV tiles per outer iter; after swapped QK^T lane (c,g) holds P at
// k=g*4+r for EACH tile, and the K=32 MFMA B-frag wants k'=g*8+j.
// Mapping k' = g*8 + tile*4 + r makes P (B-op, lane-local!) and V^T
// (A-op, two b64 LDS reads concatenated) use the SAME permutation of
// the 32 combined k-rows -> exact. PV: 32x K16 -> 16x K32 MFMAs
// (-33% MFMA slots, full-rate PV); waits halve (1 per 2 tiles).
// 4 wave-private buffers (16KB/wave, 64KB/block -> 2 blocks/CU);
// launch_bounds(256,2) so ~190 VGPR cannot spill (R4 lesson).
// =====================================================================
__global__ __launch_bounds__(256, 2) void attn_kernel(const u16* __restrict__ qkv,
                                                      const u16* __restrict__ vT,
                                                      u16* __restrict__ attn) {
    // 4 waves x 4 bufs x 4KB = 64 KB; epilogue reuses slab as
    // SC f32[64][66] (16.9 KB) and OT u16[64][72] (9.2 KB).
    __shared__ __align__(16) char smem[65536];
    __shared__ float LS[4][64];
    u16* SM = (u16*)smem;

    const int t = threadIdx.x, lane = t & 63, w = t >> 6;
    const int c = lane & 15, g = lane >> 4;

    // XCD-grouped bijective swizzle: 1024 blocks, 8 XCDs, 128 blocks/XCD.
    const int id = blockIdx.x;
    const int logical = (id & 7) * 128 + (id >> 3);
    const int bh = logical >> 5, qb = logical & 31;
    const int b = bh >> 4, h = bh & 15;
    const int q0 = qb * 64;
    const size_t rowbase = (size_t)b * 2048;

    const u16* kg = qkv + rowbase * 3072 + 1024 + h * 64;
    const u16* vg = vT + (size_t)bh * 64 * 2048;

    u16* WS = SM + w * 8192;  // wave-private slab (4 bufs x 2048 u16)

    // staging lane decomposition
    const int kr = lane >> 3, ks8 = lane & 7;           // K: row 0..7, chunk
    const int ksw = (ks8 ^ (kr & 7)) * 8;               // swizzled src chunk
    const int vr = lane >> 1, vh = (lane & 1) * 8;      // V: d-row, half

    // stage KV-tile `it`'s wave-slice into wave-private buffer bi.
    auto stage = [&](int it, int bi) {
        u16* B = WS + bi * 2048;
        const u16* kq = kg + (size_t)(it * 64 + w * 16) * 3072;
        const u16* vq = vg + it * 64 + w * 16;
        gl_lds16(kq + (size_t)kr * 3072 + ksw,       &B[lane * 8]);
        gl_lds16(kq + (size_t)(kr + 8) * 3072 + ksw, &B[512 + lane * 8]);
        gl_lds16(vq + (size_t)vr * 2048 + vh,        &B[1024 + lane * 8]);
        gl_lds16(vq + (size_t)(vr + 32) * 2048 + vh, &B[1536 + lane * 8]);
    };

    // Q B-fragments hoisted: qf[jn][ks] covers all 64 q rows of the block.
    s16x8 qf[4][2];
    {
        const u16* qg = qkv + (rowbase + q0) * 3072 + h * 64;
#pragma unroll
        for (int jn = 0; jn < 4; jn++)
#pragma unroll
            for (int ks = 0; ks < 2; ks++)
                qf[jn][ks] = *(const s16x8*)&qg[(size_t)(jn * 16 + c) * 3072 +
                                                ks * 32 + g * 8];
    }

    stage(0, 0);
    stage(1, 1);
    stage(2, 2);
    stage(3, 3);

    f32x4 acc[4][4] = {};   // O^T partial: [im: d-tile][jn: q-tile]
    float ls[4] = {};       // lane-local lsum partial per q-tile

    for (int j = 0; j < 16; j++) {
        // counted per-wave wait: tiles 2j,2j+1 landed; 2 stages in flight.
        if (j < 15)
            asm volatile("s_waitcnt vmcnt(8)" ::: "memory");
        else
            asm volatile("s_waitcnt vmcnt(0)" ::: "memory");
        __builtin_amdgcn_sched_barrier(0);

        const u16* Kb0 = WS + ((2 * j) & 3) * 2048;
        const u16* Kb1 = WS + ((2 * j + 1) & 3) * 2048;
        const u16* Vb0 = Kb0 + 1024;
        const u16* Vb1 = Kb1 + 1024;

        // K A-frags for both tiles (slice rows = c, d = ks*32+g*8, XOR'd)
        s16x8 kf0[2], kf1[2];
#pragma unroll
        for (int ks = 0; ks < 2; ks++) {
            const int sw = ((ks * 4 + g) ^ (c & 7)) * 8;
            kf0[ks] = *(const s16x8*)&Kb0[c * 64 + sw];
            kf1[ks] = *(const s16x8*)&Kb1[c * 64 + sw];
        }
        // V^T A-frags: k' = g*8 + tile*4 + r  (two b64 reads concatenated)
        s16x8 vf[4];
#pragma unroll
        for (int im = 0; im < 4; im++) {
            s16x4 v0 = *(const s16x4*)&Vb0[(im * 16 + c) * 16 + g * 4];
            s16x4 v1 = *(const s16x4*)&Vb1[(im * 16 + c) * 16 + g * 4];
            vf[im] = __builtin_shufflevector(v0, v1, 0, 1, 2, 3, 4, 5, 6, 7);
        }

        s16x8 pb[4];
        // ---- tile 0: QK^T + softmax -> pb[.][0..3]
        {
            f32x4 sc[4] = {};
            __builtin_amdgcn_s_setprio(1);
#pragma unroll
            for (int ks = 0; ks < 2; ks++)
#pragma unroll
                for (int jn = 0; jn < 4; jn++)
                    sc[jn] = mfma16(kf0[ks], qf[jn][ks], sc[jn]);
            __builtin_amdgcn_s_setprio(0);
#pragma unroll
            for (int jn = 0; jn < 4; jn++) {
                float p0 = exp2_fast(sc[jn][0]);
                float p1 = exp2_fast(sc[jn][1]);
                float p2 = exp2_fast(sc[jn][2]);
                float p3 = exp2_fast(sc[jn][3]);
                ls[jn] += (p0 + p1) + (p2 + p3);
                pb[jn][0] = f2b(p0); pb[jn][1] = f2b(p1);
                pb[jn][2] = f2b(p2); pb[jn][3] = f2b(p3);
            }
        }
        // ---- tile 1: QK^T + softmax -> pb[.][4..7]
        {
            f32x4 sc[4] = {};
            __builtin_amdgcn_s_setprio(1);
#pragma unroll
            for (int ks = 0; ks < 2; ks++)
#pragma unroll
                for (int jn = 0; jn < 4; jn++)
                    sc[jn] = mfma16(kf1[ks], qf[jn][ks], sc[jn]);
            __builtin_amdgcn_s_setprio(0);
#pragma unroll
            for (int jn = 0; jn < 4; jn++) {
                float p0 = exp2_fast(sc[jn][0]);
                float p1 = exp2_fast(sc[jn][1]);
                float p2 = exp2_fast(sc[jn][2]);
                float p3 = exp2_fast(sc[jn][3]);
                ls[jn] += (p0 + p1) + (p2 + p3);
                pb[jn][4] = f2b(p0); pb[jn][5] = f2b(p1);
                pb[jn][6] = f2b(p2); pb[jn][7] = f2b(p3);
            }
        }

        // ---- PV at K=32: O^T[d][q] += V^T(d x 32) * P^T(32 x q)
        __builtin_amdgcn_s_setprio(1);
#pragma unroll
        for (int im = 0; im < 4; im++)
#pragma unroll
            for (int jn = 0; jn < 4; jn++)
                acc[im][jn] = mfma16(vf[im], pb[jn], acc[im][jn]);
        __builtin_amdgcn_s_setprio(0);

        // refill consumed buffers with tiles 2j+4, 2j+5
        __builtin_amdgcn_sched_barrier(0);
        if (j < 14) {
            stage(2 * j + 4, (2 * j) & 3);
            stage(2 * j + 5, (2 * j + 1) & 3);
        }
    }

    // lsum: reduce across lane groups (k within slice), publish per wave
#pragma unroll
    for (int jn = 0; jn < 4; jn++) {
        float v = ls[jn];
        v += __shfl_xor(v, 16);
        v += __shfl_xor(v, 32);
        ls[jn] = v;
    }
    if (lane < 16) {
#pragma unroll
        for (int jn = 0; jn < 4; jn++) LS[w][jn * 16 + lane] = ls[jn];
    }

    // sequential k-slice reduction of O^T into wave 0 (scratch = smem)
    float* SC = (float*)smem;  // [64][66] f32
#pragma unroll
    for (int src = 3; src >= 1; --src) {
        __syncthreads();
        if (w == src) {
#pragma unroll
            for (int im = 0; im < 4; im++)
#pragma unroll
                for (int jn = 0; jn < 4; jn++)
#pragma unroll
                    for (int r = 0; r < 4; r++)
                        SC[(im * 16 + g * 4 + r) * 66 + jn * 16 + c] =
                            acc[im][jn][r];
        }
        __syncthreads();
        if (w == src - 1) {
#pragma unroll
            for (int im = 0; im < 4; im++)
#pragma unroll
                for (int jn = 0; jn < 4; jn++)
#pragma unroll
                    for (int r = 0; r < 4; r++)
                        acc[im][jn][r] +=
                            SC[(im * 16 + g * 4 + r) * 66 + jn * 16 + c];
        }
    }
    __syncthreads();

    // wave 0: scale by 1/lsum, write q-major tile for coalesced store
    u16* OT = (u16*)smem;  // [64][72] u16
    if (w == 0) {
#pragma unroll
        for (int jn = 0; jn < 4; jn++) {
            const int q = jn * 16 + c;
            const float inv = 1.f / (LS[0][q] + LS[1][q] + LS[2][q] + LS[3][q]);
#pragma unroll
            for (int im = 0; im < 4; im++)
#pragma unroll
                for (int r = 0; r < 4; r++)
                    OT[q * 72 + im * 16 + g * 4 + r] = f2b(acc[im][jn][r] * inv);
        }
    }
    __syncthreads();

    // coalesced store: thread t -> q = t>>2, d-chunk = (t&3)*16
    {
        const int q = t >> 2, d0 = (t & 3) * 16;
        const int grow = b * 2048 + q0 + q;
        u16* dst = attn + (size_t)grow * 1024 + h * 64 + d0;
        *(s16x8*)dst = *(const s16x8*)&OT[q * 72 + d0];
        *((s16x8*)dst + 1) = *((const s16x8*)&OT[q * 72 + d0] + 1);
    }
}

// =====================================================================
extern "C" void kernel_launch(void* const* d_in, const int* in_sizes, int n_in,
                              void* d_out, int out_size, void* d_ws, size_t ws_size,
                              hipStream_t stream) {
    const float* x = (const float*)d_in[0];
    const float* wq = (const float*)d_in[1];
    const float* bq = (const float*)d_in[2];
    const float* wk = (const float*)d_in[3];
    const float* bk = (const float*)d_in[4];
    const float* wv = (const float*)d_in[5];
    const float* bv = (const float*)d_in[6];
    const float* wo = (const float*)d_in[7];
    const float* bo = (const float*)d_in[8];
    const float* scale1 = (const float*)d_in[9];
    const float* scale2 = (const float*)d_in[10];
    const float* w1 = (const float*)d_in[11];
    const float* b1 = (const float*)d_in[12];
    const float* w2 = (const float*)d_in[13];
    const float* b2 = (const float*)d_in[14];
    float* out = (float*)d_out;

    char* ws = (char*)d_ws;
    size_t off = 0;
    auto alloc = [&](size_t bytes) -> char* {
        char* p = ws + off;
        off += (bytes + 255) & ~(size_t)255;
        return p;
    };
    u16* wqkvT = (u16*)alloc((size_t)3072 * 1024 * 2);   //  6 MB  [ws+0]
    u16* woT   = (u16*)alloc((size_t)1024 * 1024 * 2);   //  2 MB
    u16* w1T   = (u16*)alloc((size_t)4096 * 1024 * 2);   //  8 MB
    u16* w2T   = (u16*)alloc((size_t)1024 * 4096 * 2);   //  8 MB
    float* bqkv = (float*)alloc(3072 * 4);
    u16* xn    = (u16*)alloc((size_t)4096 * 1024 * 2);   //  8 MB
    u16* qkv   = (u16*)alloc((size_t)4096 * 3072 * 2);   // 24 MB
    u16* vT    = (u16*)alloc((size_t)32 * 64 * 2048 * 2);//  8 MB
    u16* attnb = (u16*)alloc((size_t)4096 * 1024 * 2);   //  8 MB
    float* y1  = (float*)alloc((size_t)4096 * 1024 * 4); // 16 MB
    u16* hbuf  = (u16*)alloc((size_t)4096 * 4096 * 2);   // 32 MB

    const size_t SPLIT = (size_t)4096 * 1024;
    Ptr4 po; po.p[0] = (float*)qkv; po.p[1] = (float*)qkv + SPLIT;
    po.p[2] = nullptr; po.p[3] = nullptr;
    Ptr4 pf; pf.p[0] = (float*)xn; pf.p[1] = (float*)xn + SPLIT;
    pf.p[2] = (float*)xn + 2 * SPLIT; pf.p[3] = (float*)wqkvT;

    dim3 blk(256);

    TW6 tw;
    tw.w[0] = wq; tw.o[0] = wqkvT;                          tw.mode[0] = 1;
    tw.w[1] = wk; tw.o[1] = wqkvT + (size_t)1024 * 1024;    tw.mode[1] = 2;
    tw.w[2] = wv; tw.o[2] = wqkvT + (size_t)2048 * 1024;    tw.mode[2] = 0;
    tw.w[3] = wo; tw.o[3] = woT;                            tw.mode[3] = 0;
    tw.w[4] = w1; tw.o[4] = w1T;                            tw.mode[4] = 0;
    tw.w[5] = w2; tw.o[5] = w2T;                            tw.mode[5] = 0;
    tw.bq = bq; tw.bk = bk; tw.bv = bv; tw.bqkv = bqkv;
    prep_weights<<<dim3(128, 32, 6), blk, 0, stream>>>(tw);

    // 1. RMSNorm1
    rmsnorm_kernel<<<4096, blk, 0, stream>>>(x, scale1, xn);
    // 2. QKV GEMM (rotary + log2e pre-folded into weights/bias) -> qkv bf16
    gemm_kernel<0><<<dim3(24, 32), blk, 0, stream>>>(xn, wqkvT, bqkv, nullptr, qkv, 4096, 3072, 1024);
    // 3. per-head V transpose
    transpose_v<<<dim3(64, 2, 32), blk, 0, stream>>>(qkv, vT);
    // 4. flash attention v12 (2-tile fusion, K=32 PV, wave-private staging)
    attn_kernel<<<dim3(1024), blk, 0, stream>>>(qkv, vT, attnb);
    // 5. O-proj split-K=2
    gemm_splitk<<<dim3(8, 32, 2), blk, 0, stream>>>(attnb, woT, po, 1024, 1024, 512);
    // 6. reduce + bias + resid + RMSNorm2 -> y1 fp32, xn bf16
    reduce_kernel<2, true><<<4096, blk, 0, stream>>>(po, bo, x, scale2, y1, xn);
    // 7. FFN1 + fast exact GELU -> hbuf bf16
    gemm_kernel<2><<<dim3(32, 32), blk, 0, stream>>>(xn, w1T, b1, nullptr, hbuf, 4096, 4096, 1024);
    // 8. FFN2 split-K=4
    gemm_splitk<<<dim3(8, 32, 4), blk, 0, stream>>>(hbuf, w2T, pf, 1024, 4096, 1024);
    // 9. reduce + bias + resid -> out fp32
    reduce_kernel<4, false><<<4096, blk, 0, stream>>>(pf, b2, y1, nullptr, out, nullptr);
}

// Round 9
// 356.768 us; speedup vs baseline: 1.1916x; 1.0264x over previous
//
#include <hip/hip_runtime.h>
#include <hip/hip_bf16.h>
#include <math.h>

typedef unsigned short u16;
typedef short s16x8 __attribute__((ext_vector_type(8)));
typedef short s16x4 __attribute__((ext_vector_type(4)));
typedef __bf16 bf16x8v __attribute__((ext_vector_type(8)));
typedef float f32x4 __attribute__((ext_vector_type(4)));
typedef unsigned short u16x4 __attribute__((ext_vector_type(4)));

struct Ptr4 { float* p[4]; };
struct TW6 {
    const float* w[6]; u16* o[6]; int mode[6];
    const float *bq, *bk, *bv; float* bqkv;
};

// ---------- conversions ----------
__device__ __forceinline__ u16 f2b(float f) {
    __hip_bfloat16 h = __float2bfloat16(f);
    return __builtin_bit_cast(u16, h);
}

// ---------- raw v_exp_f32 (2^x) with portable fallback ----------
__device__ __forceinline__ float exp2_fast(float x) {
#if __has_builtin(__builtin_amdgcn_exp2f)
    return __builtin_amdgcn_exp2f(x);
#else
    return exp2f(x);
#endif
}

// ---------- MFMA wrapper (gfx950: v8bf16 operands) ----------
__device__ __forceinline__ f32x4 mfma16(s16x8 a, s16x8 b, f32x4 c) {
    return __builtin_amdgcn_mfma_f32_16x16x32_bf16(
        __builtin_bit_cast(bf16x8v, a), __builtin_bit_cast(bf16x8v, b), c, 0, 0, 0);
}

// ---------- async global->LDS, 16B per lane ----------
__device__ __forceinline__ void gl_lds16(const void* g, void* l) {
    typedef const unsigned int __attribute__((address_space(1))) * gp_t;
    typedef unsigned int __attribute__((address_space(3))) * lp_t;
    __builtin_amdgcn_global_load_lds((gp_t)(unsigned long long)g,
                                     (lp_t)(unsigned int)(unsigned long long)l,
                                     16, 0, 0);
}

// ---------- cheap exact-enough GELU (tanh-form; max dev ~3e-4) ----------
__device__ __forceinline__ float gelu_fast(float v) {
    float u = 1.5957691216f * (v + 0.044715f * v * v * v);
    return v / (1.f + __expf(-u));
}

// Q-side scale: 1/sqrt(64) * log2(e) folded into wq and bq so attention
// softmax can use raw v_exp_f32 (2^x) with no per-element multiply.
#define QSCALE 0.1803368801111244f

// =====================================================================
// Unified weight prep (one launch): grid (128, 32, 6).
// =====================================================================
__global__ __launch_bounds__(256) void prep_weights(TW6 io) {
    const int z = blockIdx.z, bx = blockIdx.x, by = blockIdx.y;
    const float* W; u16* Wt; int mode = 0, N_, K_, n0, k0;
    if (z < 4) {
        if (bx >= 32) {
            if (z == 0 && bx < 44 && by == 0) {
                const int i = (bx - 32) * 256 + threadIdx.x;  // 0..3071
                const int d = i & 1023;
                const int dp = (d & ~63) | ((d + 63) & 63);
                float v;
                if (i < 1024) v = QSCALE * (io.bq[d] - io.bq[dp]);
                else if (i < 2048) v = io.bk[d] - io.bk[dp];
                else v = io.bv[d];
                io.bqkv[i] = v;
            }
            return;
        }
        W = io.w[z]; Wt = io.o[z]; mode = io.mode[z];
        N_ = 1024; K_ = 1024; n0 = bx * 32; k0 = by * 32;
    } else if (z == 4) {
        W = io.w[4]; Wt = io.o[4]; N_ = 4096; K_ = 1024; n0 = bx * 32; k0 = by * 32;
    } else {
        W = io.w[5]; Wt = io.o[5]; N_ = 1024; K_ = 4096; n0 = by * 32; k0 = bx * 32;
    }
    __shared__ u16 tile[32][33];
    const int tx = threadIdx.x & 31, ty = threadIdx.x >> 5;
    const int n = n0 + tx;
    const int np = (n & ~63) | ((n + 63) & 63);
    const float s = (mode == 1) ? QSCALE : 1.f;
#pragma unroll
    for (int i = 0; i < 32; i += 8) {
        const size_t r = (size_t)(k0 + ty + i) * N_;
        float v = W[r + n];
        if (mode) v = (v - W[r + np]) * s;
        tile[ty + i][tx] = f2b(v);
    }
    __syncthreads();
#pragma unroll
    for (int i = 0; i < 32; i += 8)
        Wt[(size_t)(n0 + ty + i) * K_ + k0 + tx] = tile[tx][ty + i];
}

// =====================================================================
// V transpose: qkv[b*2048+n][2048+h*64+d] -> vT[(bh)*64+d][n] (per-head)
// =====================================================================
__global__ __launch_bounds__(256) void transpose_v(const u16* __restrict__ qkv,
                                                   u16* __restrict__ vT) {
    __shared__ u16 tile[32][33];
    const int tx = threadIdx.x & 31, ty = threadIdx.x >> 5;
    const int n0 = blockIdx.x * 32, d0 = blockIdx.y * 32, bh = blockIdx.z;
    const int b = bh >> 4, h = bh & 15;
#pragma unroll
    for (int i = 0; i < 32; i += 8)
        tile[ty + i][tx] =
            qkv[(size_t)(b * 2048 + n0 + ty + i) * 3072 + 2048 + h * 64 + d0 + tx];
    __syncthreads();
#pragma unroll
    for (int i = 0; i < 32; i += 8)
        vT[((size_t)bh * 64 + d0 + ty + i) * 2048 + n0 + tx] = tile[tx][ty + i];
}

// =====================================================================
// RMSNorm: fp32 in [rows, 1024] -> bf16 out
// =====================================================================
__global__ __launch_bounds__(256) void rmsnorm_kernel(const float* __restrict__ x,
                                                      const float* __restrict__ scale,
                                                      u16* __restrict__ out) {
    __shared__ float red[4];
    const int t = threadIdx.x, row = blockIdx.x;
    const float4* xr = (const float4*)(x + (size_t)row * 1024);
    float4 v = xr[t];
    float ss = v.x * v.x + v.y * v.y + v.z * v.z + v.w * v.w;
#pragma unroll
    for (int off = 1; off < 64; off <<= 1) ss += __shfl_xor(ss, off);
    if ((t & 63) == 0) red[t >> 6] = ss;
    __syncthreads();
    float tot = red[0] + red[1] + red[2] + red[3];
    float inv = 1.f / (sqrtf(tot * (1.f / 1024.f)) + 1e-8f);
    const float4* sr = (const float4*)scale;
    float4 s = sr[t];
    u16x4 o;
    o[0] = f2b(v.x * inv * s.x);
    o[1] = f2b(v.y * inv * s.y);
    o[2] = f2b(v.z * inv * s.z);
    o[3] = f2b(v.w * inv * s.w);
    ((u16x4*)(out + (size_t)row * 1024))[t] = o;
}

// =====================================================================
// bf16 MFMA GEMM, 128x128 tile, BK=64, 4 waves, 32 KB LDS (m97-style).
// EPI: 0 = bf16(AB+bias); 1 = f32(AB+bias+resid); 2 = bf16(gelu(AB+bias))
// =====================================================================
template <int EPI>
__global__ __launch_bounds__(256) void gemm_kernel(const u16* __restrict__ A,
                                                   const u16* __restrict__ Bt,
                                                   const float* __restrict__ bias,
                                                   const float* __restrict__ resid,
                                                   void* __restrict__ outp,
                                                   int M, int N, int K) {
    __shared__ __align__(16) u16 As[128 * 64];
    __shared__ __align__(16) u16 Bs[128 * 64];
    const int t = threadIdx.x, lane = t & 63;
    const int w = t >> 6, wm = (w >> 1) * 64, wn = (w & 1) * 64;
    const int c = lane & 15, qd = lane >> 4;
    const int n0 = blockIdx.x * 128, m0 = blockIdx.y * 128;

    const int srow = t >> 3;                          // 0..31
    const int sch8 = ((t & 7) ^ (srow & 7)) * 8;      // swizzled source col
    const u16* Ag = A + (size_t)(m0 + srow) * K + sch8;
    const u16* Bg = Bt + (size_t)(n0 + srow) * K + sch8;
    const size_t rstride = (size_t)32 * K;

    f32x4 acc[4][4] = {};
    for (int kt = 0; kt < K; kt += 64) {
        __syncthreads();
#pragma unroll
        for (int g = 0; g < 4; g++) {
            gl_lds16(Ag + g * rstride, &As[t * 8 + g * 2048]);
            gl_lds16(Bg + g * rstride, &Bs[t * 8 + g * 2048]);
        }
        Ag += 64;
        Bg += 64;
        __syncthreads();
#pragma unroll
        for (int s = 0; s < 2; s++) {
            s16x8 a[4], b[4];
#pragma unroll
            for (int im = 0; im < 4; im++)
                a[im] = *(const s16x8*)&As[(wm + im * 16 + c) * 64 +
                                           (((s * 4 + qd) ^ (c & 7)) * 8)];
#pragma unroll
            for (int jn = 0; jn < 4; jn++)
                b[jn] = *(const s16x8*)&Bs[(wn + jn * 16 + c) * 64 +
                                           (((s * 4 + qd) ^ (c & 7)) * 8)];
#pragma unroll
            for (int im = 0; im < 4; im++)
#pragma unroll
                for (int jn = 0; jn < 4; jn++)
                    acc[im][jn] = mfma16(a[im], b[jn], acc[im][jn]);
        }
    }

#pragma unroll
    for (int im = 0; im < 4; im++) {
#pragma unroll
        for (int jn = 0; jn < 4; jn++) {
            const int colg = n0 + wn + jn * 16 + c;
            const float bv = bias[colg];
#pragma unroll
            for (int r = 0; r < 4; r++) {
                const int rowg = m0 + wm + im * 16 + qd * 4 + r;
                const size_t off = (size_t)rowg * N + colg;
                float v = acc[im][jn][r] + bv;
                if (EPI == 0) {
                    ((u16*)outp)[off] = f2b(v);
                } else if (EPI == 1) {
                    ((float*)outp)[off] = v + resid[off];
                } else {
                    ((u16*)outp)[off] = f2b(gelu_fast(v));
                }
            }
        }
    }
}

// =====================================================================
// 256x256 8-phase GEMM (T3+T4 template) with GELU epilogue.  FIXED R9:
// counted-vmcnt PUBLICATION protocol.  vmcnt(N) is per-wave, but every
// half-tile stage is distributed across all 8 waves -> a wave's own
// vmcnt proves only ITS loads landed.  The wait must therefore sit
// immediately BEFORE an s_barrier, and the dependent ds_reads AFTER it
// (8 x "mine landed" + barrier = "all landed").  R8 had vmcnt at the
// START of the consuming phase, reads issued pre-barrier -> race -> NaN.
//  - prologue: 12 loads; vmcnt(4) retires slot0's 8; s_barrier publishes.
//  - end of phase 3 (post-MFMA): vmcnt(4) (last iter: 0) publishes slot1.
//  - end of phase 7 (post-MFMA): vmcnt(4) publishes next slot0 (skip last).
//  - bias preloaded to regs behind an asm memory fence BEFORE prologue so
//    LICM cannot inject loop-invariant global loads into the counted
//    stream (they retire inside the prologue's vmcnt(4)).
// Load accounting (steady state): 12 outstanding at each wait, retire 8,
// keep 4 in flight -- verified per-iter including it=7 edge (vmcnt(0)).
// =====================================================================
__global__ __launch_bounds__(512, 2) void gemm256_gelu(const u16* __restrict__ A,
                                                       const u16* __restrict__ Bt,
                                                       const float* __restrict__ bias,
                                                       u16* __restrict__ outp) {
    __shared__ __align__(16) u16 sm[65536];  // 128 KB
    u16* As = sm;            // [2][16384]
    u16* Bs = sm + 32768;    // [2][16384]

    const int t = threadIdx.x, lane = t & 63, w = t >> 6;
    const int c = lane & 15, qd = lane >> 4;
    const int wm = (w >> 2) * 128, wn = (w & 3) * 64;

    // XCD-grouped bijective swizzle over 256 blocks (nwg%8==0).
    const int id = (int)blockIdx.x;
    const int l = (id & 7) * 32 + (id >> 3);
    const int m0 = (l >> 4) * 256, n0 = (l & 15) * 256;

    const int srow = t >> 3;                       // 0..63
    const int sch8 = ((t & 7) ^ (srow & 7)) * 8;   // swizzled source chunk
    const u16* Ag = A + (size_t)(m0 + srow) * 1024 + sch8;
    const u16* Bg = Bt + (size_t)(n0 + srow) * 1024 + sch8;

    // bias -> regs BEFORE any counted load; fence pins program order.
    float bv[4];
#pragma unroll
    for (int n = 0; n < 4; ++n) bv[n] = bias[n0 + wn + n * 16 + c];
    asm volatile("" ::: "memory");

    // stage one half-tile (128 rows x 64 k) = 2 x gl_lds16 per thread
    auto stageA = [&](int kt, int h, int s) {
        const u16* src = Ag + (size_t)(h * 128) * 1024 + kt * 64;
        u16* dst = As + s * 16384 + h * 8192 + t * 8;
        gl_lds16(src, dst);
        gl_lds16(src + (size_t)64 * 1024, dst + 4096);
    };
    auto stageB = [&](int kt, int h, int s) {
        const u16* src = Bg + (size_t)(h * 128) * 1024 + kt * 64;
        u16* dst = Bs + s * 16384 + h * 8192 + t * 8;
        gl_lds16(src, dst);
        gl_lds16(src + (size_t)64 * 1024, dst + 4096);
    };

    // prologue: K-tile 0 (A+B) -> slot0; B of K-tile 1 -> slot1
    stageA(0, 0, 0); stageA(0, 1, 0);
    stageB(0, 0, 0); stageB(0, 1, 0);
    stageB(1, 0, 1); stageB(1, 1, 1);
    asm volatile("s_waitcnt vmcnt(4)" ::: "memory");
    __builtin_amdgcn_s_barrier();              // publish slot0
    __builtin_amdgcn_sched_barrier(0);

    f32x4 acc[8][4] = {};

    for (int it = 0; it < 8; ++it) {
        const int ktA = 2 * it, ktB = 2 * it + 1;
        s16x8 bf[4][2];

        // ======== phases 0-3: slot0 (K-tile ktA) ========
#pragma unroll
        for (int q = 0; q < 4; ++q) {
            s16x8 af[2][2];
            if (q == 0) {
#pragma unroll
                for (int n = 0; n < 4; ++n)
#pragma unroll
                    for (int ks = 0; ks < 2; ++ks)
                        bf[n][ks] = *(const s16x8*)&Bs[(wn + n * 16 + c) * 64 +
                                                       (((ks * 4 + qd) ^ (c & 7)) * 8)];
            }
#pragma unroll
            for (int mm = 0; mm < 2; ++mm)
#pragma unroll
                for (int ks = 0; ks < 2; ++ks)
                    af[mm][ks] = *(const s16x8*)&As[(wm + (2 * q + mm) * 16 + c) * 64 +
                                                    (((ks * 4 + qd) ^ (c & 7)) * 8)];
            if (q == 0) {
                stageA(ktB, 0, 1);
            } else if (q == 1) {
                stageA(ktB, 1, 1);
                if (ktA + 2 < 16) stageB(ktA + 2, 0, 0);
            } else if (q == 2) {
                if (ktA + 2 < 16) stageB(ktA + 2, 1, 0);
            }
            __builtin_amdgcn_s_barrier();
            asm volatile("s_waitcnt lgkmcnt(0)" ::: "memory");
            __builtin_amdgcn_sched_barrier(0);
            __builtin_amdgcn_s_setprio(1);
#pragma unroll
            for (int mm = 0; mm < 2; ++mm)
#pragma unroll
                for (int n = 0; n < 4; ++n)
#pragma unroll
                    for (int ks = 0; ks < 2; ++ks)
                        acc[2 * q + mm][n] =
                            mfma16(af[mm][ks], bf[n][ks], acc[2 * q + mm][n]);
            __builtin_amdgcn_s_setprio(0);
            if (q == 3) {   // publish slot1 for phases 4-7
                if (it < 7)
                    asm volatile("s_waitcnt vmcnt(4)" ::: "memory");
                else
                    asm volatile("s_waitcnt vmcnt(0)" ::: "memory");
            }
            __builtin_amdgcn_s_barrier();
        }

        // ======== phases 4-7: slot1 (K-tile ktB) ========
#pragma unroll
        for (int q = 0; q < 4; ++q) {
            s16x8 af[2][2];
            if (q == 0) {
#pragma unroll
                for (int n = 0; n < 4; ++n)
#pragma unroll
                    for (int ks = 0; ks < 2; ++ks)
                        bf[n][ks] = *(const s16x8*)&Bs[16384 + (wn + n * 16 + c) * 64 +
                                                       (((ks * 4 + qd) ^ (c & 7)) * 8)];
            }
#pragma unroll
            for (int mm = 0; mm < 2; ++mm)
#pragma unroll
                for (int ks = 0; ks < 2; ++ks)
                    af[mm][ks] = *(const s16x8*)&As[16384 + (wm + (2 * q + mm) * 16 + c) * 64 +
                                                    (((ks * 4 + qd) ^ (c & 7)) * 8)];
            if (q == 0) {
                if (ktA + 2 < 16) stageA(ktA + 2, 0, 0);
            } else if (q == 1) {
                if (ktA + 2 < 16) stageA(ktA + 2, 1, 0);
            } else if (q == 2) {
                if (ktB + 2 < 16) stageB(ktB + 2, 0, 1);
            } else {
                if (ktB + 2 < 16) stageB(ktB + 2, 1, 1);
            }
            __builtin_amdgcn_s_barrier();
            asm volatile("s_waitcnt lgkmcnt(0)" ::: "memory");
            __builtin_amdgcn_sched_barrier(0);
            __builtin_amdgcn_s_setprio(1);
#pragma unroll
            for (int mm = 0; mm < 2; ++mm)
#pragma unroll
                for (int n = 0; n < 4; ++n)
#pragma unroll
                    for (int ks = 0; ks < 2; ++ks)
                        acc[2 * q + mm][n] =
                            mfma16(af[mm][ks], bf[n][ks], acc[2 * q + mm][n]);
            __builtin_amdgcn_s_setprio(0);
            if (q == 3 && it < 7)   // publish next slot0
                asm volatile("s_waitcnt vmcnt(4)" ::: "memory");
            __builtin_amdgcn_s_barrier();
        }
    }

    // epilogue: gelu(acc + bias) -> bf16
#pragma unroll
    for (int m = 0; m < 8; ++m)
#pragma unroll
        for (int n = 0; n < 4; ++n) {
            const int colg = n0 + wn + n * 16 + c;
#pragma unroll
            for (int r = 0; r < 4; ++r) {
                const int rowg = m0 + wm + m * 16 + qd * 4 + r;
                outp[(size_t)rowg * 4096 + colg] =
                    f2b(gelu_fast(acc[m][n][r] + bv[n]));
            }
        }
}

// =====================================================================
// Split-K GEMM, BK=64 (same swizzle): blockIdx.z = split; fp32 partials.
// =====================================================================
__global__ __launch_bounds__(256) void gemm_splitk(const u16* __restrict__ A,
                                                   const u16* __restrict__ Bt,
                                                   Ptr4 parts,
                                                   int N, int Ktot, int Kc) {
    __shared__ __align__(16) u16 As[128 * 64];
    __shared__ __align__(16) u16 Bs[128 * 64];
    const int t = threadIdx.x, lane = t & 63;
    const int w = t >> 6, wm = (w >> 1) * 64, wn = (w & 1) * 64;
    const int c = lane & 15, qd = lane >> 4;
    const int n0 = blockIdx.x * 128, m0 = blockIdx.y * 128;
    const int z = blockIdx.z;
    float* out = parts.p[z];

    const int srow = t >> 3;
    const int sch8 = ((t & 7) ^ (srow & 7)) * 8;
    const u16* Ag = A + (size_t)(m0 + srow) * Ktot + z * Kc + sch8;
    const u16* Bg = Bt + (size_t)(n0 + srow) * Ktot + z * Kc + sch8;
    const size_t rstride = (size_t)32 * Ktot;

    f32x4 acc[4][4] = {};
    for (int kt = 0; kt < Kc; kt += 64) {
        __syncthreads();
#pragma unroll
        for (int g = 0; g < 4; g++) {
            gl_lds16(Ag + g * rstride, &As[t * 8 + g * 2048]);
            gl_lds16(Bg + g * rstride, &Bs[t * 8 + g * 2048]);
        }
        Ag += 64;
        Bg += 64;
        __syncthreads();
#pragma unroll
        for (int s = 0; s < 2; s++) {
            s16x8 a[4], b[4];
#pragma unroll
            for (int im = 0; im < 4; im++)
                a[im] = *(const s16x8*)&As[(wm + im * 16 + c) * 64 +
                                           (((s * 4 + qd) ^ (c & 7)) * 8)];
#pragma unroll
            for (int jn = 0; jn < 4; jn++)
                b[jn] = *(const s16x8*)&Bs[(wn + jn * 16 + c) * 64 +
                                           (((s * 4 + qd) ^ (c & 7)) * 8)];
#pragma unroll
            for (int im = 0; im < 4; im++)
#pragma unroll
                for (int jn = 0; jn < 4; jn++)
                    acc[im][jn] = mfma16(a[im], b[jn], acc[im][jn]);
        }
    }

#pragma unroll
    for (int im = 0; im < 4; im++)
#pragma unroll
        for (int jn = 0; jn < 4; jn++) {
            const int colg = n0 + wn + jn * 16 + c;
#pragma unroll
            for (int r = 0; r < 4; r++) {
                const int rowg = m0 + wm + im * 16 + qd * 4 + r;
                out[(size_t)rowg * N + colg] = acc[im][jn][r];
            }
        }
}

// =====================================================================
// Split-K reduce. One block per row (1024 cols, float4/thread).
// =====================================================================
template <int S, bool NORM>
__global__ __launch_bounds__(256) void reduce_kernel(Ptr4 parts,
                                                     const float* __restrict__ bias,
                                                     const float* __restrict__ resid,
                                                     const float* __restrict__ scale,
                                                     float* __restrict__ yout,
                                                     u16* __restrict__ xnout) {
    __shared__ float red[4];
    const int t = threadIdx.x, row = blockIdx.x;
    const size_t base = (size_t)row * 1024;
    float4 v = ((const float4*)(resid + base))[t];
    float4 bv = ((const float4*)bias)[t];
    v.x += bv.x; v.y += bv.y; v.z += bv.z; v.w += bv.w;
#pragma unroll
    for (int s = 0; s < S; s++) {
        float4 pv = ((const float4*)(parts.p[s] + base))[t];
        v.x += pv.x; v.y += pv.y; v.z += pv.z; v.w += pv.w;
    }
    ((float4*)(yout + base))[t] = v;
    if (NORM) {
        float ss = v.x * v.x + v.y * v.y + v.z * v.z + v.w * v.w;
#pragma unroll
        for (int off = 1; off < 64; off <<= 1) ss += __shfl_xor(ss, off);
        if ((t & 63) == 0) red[t >> 6] = ss;
        __syncthreads();
        float tot = red[0] + red[1] + red[2] + red[3];
        float inv = 1.f / (sqrtf(tot * (1.f / 1024.f)) + 1e-8f);
        float4 s = ((const float4*)scale)[t];
        u16x4 o;
        o[0] = f2b(v.x * inv * s.x);
        o[1] = f2b(v.y * inv * s.y);
        o[2] = f2b(v.z * inv * s.z);
        o[3] = f2b(v.w * inv * s.w);
        ((u16x4*)(xnout + base))[t] = o;
    }
}

// =====================================================================
// Flash attention v12: 2-tile fusion + K=32 PV (see R7 notes).
// =====================================================================
__global__ __launch_bounds__(256, 2) void attn_kernel(const u16* __restrict__ qkv,
                                                      const u16* __restrict__ vT,
                                                      u16* __restrict__ attn) {
    __shared__ __align__(16) char smem[65536];
    __shared__ float LS[4][64];
    u16* SM = (u16*)smem;

    const int t = threadIdx.x, lane = t & 63, w = t >> 6;
    const int c = lane & 15, g = lane >> 4;

    const int id = blockIdx.x;
    const int logical = (id & 7) * 128 + (id >> 3);
    const int bh = logical >> 5, qb = logical & 31;
    const int b = bh >> 4, h = bh & 15;
    const int q0 = qb * 64;
    const size_t rowbase = (size_t)b * 2048;

    const u16* kg = qkv + rowbase * 3072 + 1024 + h * 64;
    const u16* vg = vT + (size_t)bh * 64 * 2048;

    u16* WS = SM + w * 8192;

    const int kr = lane >> 3, ks8 = lane & 7;
    const int ksw = (ks8 ^ (kr & 7)) * 8;
    const int vr = lane >> 1, vh = (lane & 1) * 8;

    auto stage = [&](int it, int bi) {
        u16* B = WS + bi * 2048;
        const u16* kq = kg + (size_t)(it * 64 + w * 16) * 3072;
        const u16* vq = vg + it * 64 + w * 16;
        gl_lds16(kq + (size_t)kr * 3072 + ksw,       &B[lane * 8]);
        gl_lds16(kq + (size_t)(kr + 8) * 3072 + ksw, &B[512 + lane * 8]);
        gl_lds16(vq + (size_t)vr * 2048 + vh,        &B[1024 + lane * 8]);
        gl_lds16(vq + (size_t)(vr + 32) * 2048 + vh, &B[1536 + lane * 8]);
    };

    s16x8 qf[4][2];
    {
        const u16* qg = qkv + (rowbase + q0) * 3072 + h * 64;
#pragma unroll
        for (int jn = 0; jn < 4; jn++)
#pragma unroll
            for (int ks = 0; ks < 2; ks++)
                qf[jn][ks] = *(const s16x8*)&qg[(size_t)(jn * 16 + c) * 3072 +
                                                ks * 32 + g * 8];
    }

    stage(0, 0);
    stage(1, 1);
    stage(2, 2);
    stage(3, 3);

    f32x4 acc[4][4] = {};
    float ls[4] = {};

    for (int j = 0; j < 16; j++) {
        if (j < 15)
            asm volatile("s_waitcnt vmcnt(8)" ::: "memory");
        else
            asm volatile("s_waitcnt vmcnt(0)" ::: "memory");
        __builtin_amdgcn_sched_barrier(0);

        const u16* Kb0 = WS + ((2 * j) & 3) * 2048;
        const u16* Kb1 = WS + ((2 * j + 1) & 3) * 2048;
        const u16* Vb0 = Kb0 + 1024;
        const u16* Vb1 = Kb1 + 1024;

        s16x8 kf0[2], kf1[2];
#pragma unroll
        for (int ks = 0; ks < 2; ks++) {
            const int sw = ((ks * 4 + g) ^ (c & 7)) * 8;
            kf0[ks] = *(const s16x8*)&Kb0[c * 64 + sw];
            kf1[ks] = *(const s16x8*)&Kb1[c * 64 + sw];
        }
        s16x8 vf[4];
#pragma unroll
        for (int im = 0; im < 4; im++) {
            s16x4 v0 = *(const s16x4*)&Vb0[(im * 16 + c) * 16 + g * 4];
            s16x4 v1 = *(const s16x4*)&Vb1[(im * 16 + c) * 16 + g * 4];
            vf[im] = __builtin_shufflevector(v0, v1, 0, 1, 2, 3, 4, 5, 6, 7);
        }

        s16x8 pb[4];
        {
            f32x4 sc[4] = {};
            __builtin_amdgcn_s_setprio(1);
#pragma unroll
            for (int ks = 0; ks < 2; ks++)
#pragma unroll
                for (int jn = 0; jn < 4; jn++)
                    sc[jn] = mfma16(kf0[ks], qf[jn][ks], sc[jn]);
            __builtin_amdgcn_s_setprio(0);
#pragma unroll
            for (int jn = 0; jn < 4; jn++) {
                float p0 = exp2_fast(sc[jn][0]);
                float p1 = exp2_fast(sc[jn][1]);
                float p2 = exp2_fast(sc[jn][2]);
                float p3 = exp2_fast(sc[jn][3]);
                ls[jn] += (p0 + p1) + (p2 + p3);
                pb[jn][0] = f2b(p0); pb[jn][1] = f2b(p1);
                pb[jn][2] = f2b(p2); pb[jn][3] = f2b(p3);
            }
        }
        {
            f32x4 sc[4] = {};
            __builtin_amdgcn_s_setprio(1);
#pragma unroll
            for (int ks = 0; ks < 2; ks++)
#pragma unroll
                for (int jn = 0; jn < 4; jn++)
                    sc[jn] = mfma16(kf1[ks], qf[jn][ks], sc[jn]);
            __builtin_amdgcn_s_setprio(0);
#pragma unroll
            for (int jn = 0; jn < 4; jn++) {
                float p0 = exp2_fast(sc[jn][0]);
                float p1 = exp2_fast(sc[jn][1]);
                float p2 = exp2_fast(sc[jn][2]);
                float p3 = exp2_fast(sc[jn][3]);
                ls[jn] += (p0 + p1) + (p2 + p3);
                pb[jn][4] = f2b(p0); pb[jn][5] = f2b(p1);
                pb[jn][6] = f2b(p2); pb[jn][7] = f2b(p3);
            }
        }

        __builtin_amdgcn_s_setprio(1);
#pragma unroll
        for (int im = 0; im < 4; im++)
#pragma unroll
            for (int jn = 0; jn < 4; jn++)
                acc[im][jn] = mfma16(vf[im], pb[jn], acc[im][jn]);
        __builtin_amdgcn_s_setprio(0);

        __builtin_amdgcn_sched_barrier(0);
        if (j < 14) {
            stage(2 * j + 4, (2 * j) & 3);
            stage(2 * j + 5, (2 * j + 1) & 3);
        }
    }

#pragma unroll
    for (int jn = 0; jn < 4; jn++) {
        float v = ls[jn];
        v += __shfl_xor(v, 16);
        v += __shfl_xor(v, 32);
        ls[jn] = v;
    }
    if (lane < 16) {
#pragma unroll
        for (int jn = 0; jn < 4; jn++) LS[w][jn * 16 + lane] = ls[jn];
    }

    float* SC = (float*)smem;
#pragma unroll
    for (int src = 3; src >= 1; --src) {
        __syncthreads();
        if (w == src) {
#pragma unroll
            for (int im = 0; im < 4; im++)
#pragma unroll
                for (int jn = 0; jn < 4; jn++)
#pragma unroll
                    for (int r = 0; r < 4; r++)
                        SC[(im * 16 + g * 4 + r) * 66 + jn * 16 + c] =
                            acc[im][jn][r];
        }
        __syncthreads();
        if (w == src - 1) {
#pragma unroll
            for (int im = 0; im < 4; im++)
#pragma unroll
                for (int jn = 0; jn < 4; jn++)
#pragma unroll
                    for (int r = 0; r < 4; r++)
                        acc[im][jn][r] +=
                            SC[(im * 16 + g * 4 + r) * 66 + jn * 16 + c];
        }
    }
    __syncthreads();

    u16* OT = (u16*)smem;
    if (w == 0) {
#pragma unroll
        for (int jn = 0; jn < 4; jn++) {
            const int q = jn * 16 + c;
            const float inv = 1.f / (LS[0][q] + LS[1][q] + LS[2][q] + LS[3][q]);
#pragma unroll
            for (int im = 0; im < 4; im++)
#pragma unroll
                for (int r = 0; r < 4; r++)
                    OT[q * 72 + im * 16 + g * 4 + r] = f2b(acc[im][jn][r] * inv);
        }
    }
    __syncthreads();

    {
        const int q = t >> 2, d0 = (t & 3) * 16;
        const int grow = b * 2048 + q0 + q;
        u16* dst = attn + (size_t)grow * 1024 + h * 64 + d0;
        *(s16x8*)dst = *(const s16x8*)&OT[q * 72 + d0];
        *((s16x8*)dst + 1) = *((const s16x8*)&OT[q * 72 + d0] + 1);
    }
}

// =====================================================================
extern "C" void kernel_launch(void* const* d_in, const int* in_sizes, int n_in,
                              void* d_out, int out_size, void* d_ws, size_t ws_size,
                              hipStream_t stream) {
    const float* x = (const float*)d_in[0];
    const float* wq = (const float*)d_in[1];
    const float* bq = (const float*)d_in[2];
    const float* wk = (const float*)d_in[3];
    const float* bk = (const float*)d_in[4];
    const float* wv = (const float*)d_in[5];
    const float* bv = (const float*)d_in[6];
    const float* wo = (const float*)d_in[7];
    const float* bo = (const float*)d_in[8];
    const float* scale1 = (const float*)d_in[9];
    const float* scale2 = (const float*)d_in[10];
    const float* w1 = (const float*)d_in[11];
    const float* b1 = (const float*)d_in[12];
    const float* w2 = (const float*)d_in[13];
    const float* b2 = (const float*)d_in[14];
    float* out = (float*)d_out;

    char* ws = (char*)d_ws;
    size_t off = 0;
    auto alloc = [&](size_t bytes) -> char* {
        char* p = ws + off;
        off += (bytes + 255) & ~(size_t)255;
        return p;
    };
    u16* wqkvT = (u16*)alloc((size_t)3072 * 1024 * 2);   //  6 MB  [ws+0]
    u16* woT   = (u16*)alloc((size_t)1024 * 1024 * 2);   //  2 MB
    u16* w1T   = (u16*)alloc((size_t)4096 * 1024 * 2);   //  8 MB
    u16* w2T   = (u16*)alloc((size_t)1024 * 4096 * 2);   //  8 MB
    float* bqkv = (float*)alloc(3072 * 4);
    u16* xn    = (u16*)alloc((size_t)4096 * 1024 * 2);   //  8 MB
    u16* qkv   = (u16*)alloc((size_t)4096 * 3072 * 2);   // 24 MB
    u16* vT    = (u16*)alloc((size_t)32 * 64 * 2048 * 2);//  8 MB
    u16* attnb = (u16*)alloc((size_t)4096 * 1024 * 2);   //  8 MB
    float* y1  = (float*)alloc((size_t)4096 * 1024 * 4); // 16 MB
    u16* hbuf  = (u16*)alloc((size_t)4096 * 4096 * 2);   // 32 MB

    const size_t SPLIT = (size_t)4096 * 1024;
    Ptr4 po; po.p[0] = (float*)qkv; po.p[1] = (float*)qkv + SPLIT;
    po.p[2] = nullptr; po.p[3] = nullptr;
    Ptr4 pf; pf.p[0] = (float*)xn; pf.p[1] = (float*)xn + SPLIT;
    pf.p[2] = (float*)xn + 2 * SPLIT; pf.p[3] = (float*)wqkvT;

    dim3 blk(256);

    TW6 tw;
    tw.w[0] = wq; tw.o[0] = wqkvT;                          tw.mode[0] = 1;
    tw.w[1] = wk; tw.o[1] = wqkvT + (size_t)1024 * 1024;    tw.mode[1] = 2;
    tw.w[2] = wv; tw.o[2] = wqkvT + (size_t)2048 * 1024;    tw.mode[2] = 0;
    tw.w[3] = wo; tw.o[3] = woT;                            tw.mode[3] = 0;
    tw.w[4] = w1; tw.o[4] = w1T;                            tw.mode[4] = 0;
    tw.w[5] = w2; tw.o[5] = w2T;                            tw.mode[5] = 0;
    tw.bq = bq; tw.bk = bk; tw.bv = bv; tw.bqkv = bqkv;
    prep_weights<<<dim3(128, 32, 6), blk, 0, stream>>>(tw);

    // 1. RMSNorm1
    rmsnorm_kernel<<<4096, blk, 0, stream>>>(x, scale1, xn);
    // 2. QKV GEMM (rotary + log2e pre-folded into weights/bias) -> qkv bf16
    gemm_kernel<0><<<dim3(24, 32), blk, 0, stream>>>(xn, wqkvT, bqkv, nullptr, qkv, 4096, 3072, 1024);
    // 3. per-head V transpose
    transpose_v<<<dim3(64, 2, 32), blk, 0, stream>>>(qkv, vT);
    // 4. flash attention v12 (2-tile fusion, K=32 PV, wave-private staging)
    attn_kernel<<<dim3(1024), blk, 0, stream>>>(qkv, vT, attnb);
    // 5. O-proj split-K=2
    gemm_splitk<<<dim3(8, 32, 2), blk, 0, stream>>>(attnb, woT, po, 1024, 1024, 512);
    // 6. reduce + bias + resid + RMSNorm2 -> y1 fp32, xn bf16
    reduce_kernel<2, true><<<4096, blk, 0, stream>>>(po, bo, x, scale2, y1, xn);
    // 7. FFN1 + fast exact GELU via 256^2 8-phase template (R9 fixed) -> hbuf
    gemm256_gelu<<<dim3(256), dim3(512), 0, stream>>>(xn, w1T, b1, hbuf);
    // 8. FFN2 split-K=4
    gemm_splitk<<<dim3(8, 32, 4), blk, 0, stream>>>(hbuf, w2T, pf, 1024, 4096, 1024);
    // 9. reduce + bias + resid -> out fp32
    reduce_kernel<4, false><<<4096, blk, 0, stream>>>(pf, b2, y1, nullptr, out, nullptr);
}

// Round 10
// 341.928 us; speedup vs baseline: 1.2433x; 1.0434x over previous
//
#include <hip/hip_runtime.h>
#include <hip/hip_bf16.h>
#include <math.h>

typedef unsigned short u16;
typedef short s16x8 __attribute__((ext_vector_type(8)));
typedef short s16x4 __attribute__((ext_vector_type(4)));
typedef __bf16 bf16x8v __attribute__((ext_vector_type(8)));
typedef float f32x4 __attribute__((ext_vector_type(4)));
typedef unsigned short u16x4 __attribute__((ext_vector_type(4)));

struct Ptr4 { float* p[4]; };
struct TW6 {
    const float* w[6]; u16* o[6]; int mode[6];
    const float *bq, *bk, *bv; float* bqkv;
};

// ---------- conversions ----------
__device__ __forceinline__ u16 f2b(float f) {
    __hip_bfloat16 h = __float2bfloat16(f);
    return __builtin_bit_cast(u16, h);
}

// ---------- raw v_exp_f32 (2^x) with portable fallback ----------
__device__ __forceinline__ float exp2_fast(float x) {
#if __has_builtin(__builtin_amdgcn_exp2f)
    return __builtin_amdgcn_exp2f(x);
#else
    return exp2f(x);
#endif
}

// ---------- MFMA wrapper (gfx950: v8bf16 operands) ----------
__device__ __forceinline__ f32x4 mfma16(s16x8 a, s16x8 b, f32x4 c) {
    return __builtin_amdgcn_mfma_f32_16x16x32_bf16(
        __builtin_bit_cast(bf16x8v, a), __builtin_bit_cast(bf16x8v, b), c, 0, 0, 0);
}

// ---------- async global->LDS, 16B per lane ----------
__device__ __forceinline__ void gl_lds16(const void* g, void* l) {
    typedef const unsigned int __attribute__((address_space(1))) * gp_t;
    typedef unsigned int __attribute__((address_space(3))) * lp_t;
    __builtin_amdgcn_global_load_lds((gp_t)(unsigned long long)g,
                                     (lp_t)(unsigned int)(unsigned long long)l,
                                     16, 0, 0);
}

// ---------- cheap exact-enough GELU (tanh-form; max dev ~3e-4) ----------
__device__ __forceinline__ float gelu_fast(float v) {
    float u = 1.5957691216f * (v + 0.044715f * v * v * v);
    return v / (1.f + __expf(-u));
}

// Q-side scale: 1/sqrt(64) * log2(e) folded into wq and bq so attention
// softmax can use raw v_exp_f32 (2^x) with no per-element multiply.
#define QSCALE 0.1803368801111244f

// =====================================================================
// Unified weight prep (one launch): grid (128, 32, 6).
// =====================================================================
__global__ __launch_bounds__(256) void prep_weights(TW6 io) {
    const int z = blockIdx.z, bx = blockIdx.x, by = blockIdx.y;
    const float* W; u16* Wt; int mode = 0, N_, K_, n0, k0;
    if (z < 4) {
        if (bx >= 32) {
            if (z == 0 && bx < 44 && by == 0) {
                const int i = (bx - 32) * 256 + threadIdx.x;  // 0..3071
                const int d = i & 1023;
                const int dp = (d & ~63) | ((d + 63) & 63);
                float v;
                if (i < 1024) v = QSCALE * (io.bq[d] - io.bq[dp]);
                else if (i < 2048) v = io.bk[d] - io.bk[dp];
                else v = io.bv[d];
                io.bqkv[i] = v;
            }
            return;
        }
        W = io.w[z]; Wt = io.o[z]; mode = io.mode[z];
        N_ = 1024; K_ = 1024; n0 = bx * 32; k0 = by * 32;
    } else if (z == 4) {
        W = io.w[4]; Wt = io.o[4]; N_ = 4096; K_ = 1024; n0 = bx * 32; k0 = by * 32;
    } else {
        W = io.w[5]; Wt = io.o[5]; N_ = 1024; K_ = 4096; n0 = by * 32; k0 = bx * 32;
    }
    __shared__ u16 tile[32][33];
    const int tx = threadIdx.x & 31, ty = threadIdx.x >> 5;
    const int n = n0 + tx;
    const int np = (n & ~63) | ((n + 63) & 63);
    const float s = (mode == 1) ? QSCALE : 1.f;
#pragma unroll
    for (int i = 0; i < 32; i += 8) {
        const size_t r = (size_t)(k0 + ty + i) * N_;
        float v = W[r + n];
        if (mode) v = (v - W[r + np]) * s;
        tile[ty + i][tx] = f2b(v);
    }
    __syncthreads();
#pragma unroll
    for (int i = 0; i < 32; i += 8)
        Wt[(size_t)(n0 + ty + i) * K_ + k0 + tx] = tile[tx][ty + i];
}

// =====================================================================
// V transpose: qkv[b*2048+n][2048+h*64+d] -> vT[(bh)*64+d][n] (per-head)
// =====================================================================
__global__ __launch_bounds__(256) void transpose_v(const u16* __restrict__ qkv,
                                                   u16* __restrict__ vT) {
    __shared__ u16 tile[32][33];
    const int tx = threadIdx.x & 31, ty = threadIdx.x >> 5;
    const int n0 = blockIdx.x * 32, d0 = blockIdx.y * 32, bh = blockIdx.z;
    const int b = bh >> 4, h = bh & 15;
#pragma unroll
    for (int i = 0; i < 32; i += 8)
        tile[ty + i][tx] =
            qkv[(size_t)(b * 2048 + n0 + ty + i) * 3072 + 2048 + h * 64 + d0 + tx];
    __syncthreads();
#pragma unroll
    for (int i = 0; i < 32; i += 8)
        vT[((size_t)bh * 64 + d0 + ty + i) * 2048 + n0 + tx] = tile[tx][ty + i];
}

// =====================================================================
// RMSNorm: fp32 in [rows, 1024] -> bf16 out
// =====================================================================
__global__ __launch_bounds__(256) void rmsnorm_kernel(const float* __restrict__ x,
                                                      const float* __restrict__ scale,
                                                      u16* __restrict__ out) {
    __shared__ float red[4];
    const int t = threadIdx.x, row = blockIdx.x;
    const float4* xr = (const float4*)(x + (size_t)row * 1024);
    float4 v = xr[t];
    float ss = v.x * v.x + v.y * v.y + v.z * v.z + v.w * v.w;
#pragma unroll
    for (int off = 1; off < 64; off <<= 1) ss += __shfl_xor(ss, off);
    if ((t & 63) == 0) red[t >> 6] = ss;
    __syncthreads();
    float tot = red[0] + red[1] + red[2] + red[3];
    float inv = 1.f / (sqrtf(tot * (1.f / 1024.f)) + 1e-8f);
    const float4* sr = (const float4*)scale;
    float4 s = sr[t];
    u16x4 o;
    o[0] = f2b(v.x * inv * s.x);
    o[1] = f2b(v.y * inv * s.y);
    o[2] = f2b(v.z * inv * s.z);
    o[3] = f2b(v.w * inv * s.w);
    ((u16x4*)(out + (size_t)row * 1024))[t] = o;
}

// =====================================================================
// 256x256 8-phase GEMM (T3+T4 template), unified (verified R9 schedule).
// Per-block K-chunk = 1024 (16 k-tiles of 64, 8 iters) for ALL uses:
//   EPI 0: bf16(AB+bias)            (QKV: Nout=3072, 192 blocks)
//   EPI 2: bf16(gelu(AB+bias))      (FFN1: Nout=4096, 256 blocks)
//   EPI 3: fp32 partial, split-K     (FFN2: z=blockIdx.y, k0=z*1024,
//                                     Ktot=4096, parts.p[z][row*1024+col])
// Publication protocol (R9-verified): stage loads are distributed across
// all 8 waves, vmcnt is per-wave -> counted wait sits immediately BEFORE
// an s_barrier; dependent ds_reads after it. vmcnt(4) at prologue end /
// phase-3 end / phase-7 end (vmcnt(0) at the final drain). Bias preloaded
// to regs behind a fence so LICM can't perturb the counted stream (EPI!=3;
// for EPI 3 the accounting is unchanged: 12-load prologue, retire 8).
// =====================================================================
template <int EPI>
__global__ __launch_bounds__(512, 2) void gemm256(const u16* __restrict__ A,
                                                  const u16* __restrict__ Bt,
                                                  const float* __restrict__ bias,
                                                  Ptr4 parts,
                                                  u16* __restrict__ outp,
                                                  int Nout, int nTN, int cpx,
                                                  int Ktot) {
    __shared__ __align__(16) u16 sm[65536];  // 128 KB
    u16* As = sm;            // [2][16384]
    u16* Bs = sm + 32768;    // [2][16384]

    const int t = threadIdx.x, lane = t & 63, w = t >> 6;
    const int c = lane & 15, qd = lane >> 4;
    const int wm = (w >> 2) * 128, wn = (w & 3) * 64;

    // XCD-grouped bijective swizzle over blockIdx.x (nwg % 8 == 0).
    const int id = (int)blockIdx.x;
    const int l = (id & 7) * cpx + (id >> 3);
    const int m0 = (l / nTN) * 256, n0 = (l % nTN) * 256;
    const int k0 = (EPI == 3) ? (int)blockIdx.y * 1024 : 0;
    float* pout = (EPI == 3) ? parts.p[blockIdx.y] : nullptr;

    const int srow = t >> 3;                       // 0..63
    const int sch8 = ((t & 7) ^ (srow & 7)) * 8;   // swizzled source chunk
    const u16* Ag = A + (size_t)(m0 + srow) * Ktot + k0 + sch8;
    const u16* Bg = Bt + (size_t)(n0 + srow) * Ktot + k0 + sch8;

    // bias -> regs BEFORE any counted load; fence pins program order.
    float bv[4];
    if (EPI != 3) {
#pragma unroll
        for (int n = 0; n < 4; ++n) bv[n] = bias[n0 + wn + n * 16 + c];
        asm volatile("" ::: "memory");
    }

    // stage one half-tile (128 rows x 64 k) = 2 x gl_lds16 per thread
    auto stageA = [&](int kt, int h, int s) {
        const u16* src = Ag + (size_t)(h * 128) * Ktot + kt * 64;
        u16* dst = As + s * 16384 + h * 8192 + t * 8;
        gl_lds16(src, dst);
        gl_lds16(src + (size_t)64 * Ktot, dst + 4096);
    };
    auto stageB = [&](int kt, int h, int s) {
        const u16* src = Bg + (size_t)(h * 128) * Ktot + kt * 64;
        u16* dst = Bs + s * 16384 + h * 8192 + t * 8;
        gl_lds16(src, dst);
        gl_lds16(src + (size_t)64 * Ktot, dst + 4096);
    };

    // prologue: K-tile 0 (A+B) -> slot0; B of K-tile 1 -> slot1
    stageA(0, 0, 0); stageA(0, 1, 0);
    stageB(0, 0, 0); stageB(0, 1, 0);
    stageB(1, 0, 1); stageB(1, 1, 1);
    asm volatile("s_waitcnt vmcnt(4)" ::: "memory");
    __builtin_amdgcn_s_barrier();              // publish slot0
    __builtin_amdgcn_sched_barrier(0);

    f32x4 acc[8][4] = {};

    for (int it = 0; it < 8; ++it) {
        const int ktA = 2 * it, ktB = 2 * it + 1;
        s16x8 bf[4][2];

        // ======== phases 0-3: slot0 (K-tile ktA) ========
#pragma unroll
        for (int q = 0; q < 4; ++q) {
            s16x8 af[2][2];
            if (q == 0) {
#pragma unroll
                for (int n = 0; n < 4; ++n)
#pragma unroll
                    for (int ks = 0; ks < 2; ++ks)
                        bf[n][ks] = *(const s16x8*)&Bs[(wn + n * 16 + c) * 64 +
                                                       (((ks * 4 + qd) ^ (c & 7)) * 8)];
            }
#pragma unroll
            for (int mm = 0; mm < 2; ++mm)
#pragma unroll
                for (int ks = 0; ks < 2; ++ks)
                    af[mm][ks] = *(const s16x8*)&As[(wm + (2 * q + mm) * 16 + c) * 64 +
                                                    (((ks * 4 + qd) ^ (c & 7)) * 8)];
            if (q == 0) {
                stageA(ktB, 0, 1);
            } else if (q == 1) {
                stageA(ktB, 1, 1);
                if (ktA + 2 < 16) stageB(ktA + 2, 0, 0);
            } else if (q == 2) {
                if (ktA + 2 < 16) stageB(ktA + 2, 1, 0);
            }
            __builtin_amdgcn_s_barrier();
            asm volatile("s_waitcnt lgkmcnt(0)" ::: "memory");
            __builtin_amdgcn_sched_barrier(0);
            __builtin_amdgcn_s_setprio(1);
#pragma unroll
            for (int mm = 0; mm < 2; ++mm)
#pragma unroll
                for (int n = 0; n < 4; ++n)
#pragma unroll
                    for (int ks = 0; ks < 2; ++ks)
                        acc[2 * q + mm][n] =
                            mfma16(af[mm][ks], bf[n][ks], acc[2 * q + mm][n]);
            __builtin_amdgcn_s_setprio(0);
            if (q == 3) {   // publish slot1 for phases 4-7
                if (it < 7)
                    asm volatile("s_waitcnt vmcnt(4)" ::: "memory");
                else
                    asm volatile("s_waitcnt vmcnt(0)" ::: "memory");
            }
            __builtin_amdgcn_s_barrier();
        }

        // ======== phases 4-7: slot1 (K-tile ktB) ========
#pragma unroll
        for (int q = 0; q < 4; ++q) {
            s16x8 af[2][2];
            if (q == 0) {
#pragma unroll
                for (int n = 0; n < 4; ++n)
#pragma unroll
                    for (int ks = 0; ks < 2; ++ks)
                        bf[n][ks] = *(const s16x8*)&Bs[16384 + (wn + n * 16 + c) * 64 +
                                                       (((ks * 4 + qd) ^ (c & 7)) * 8)];
            }
#pragma unroll
            for (int mm = 0; mm < 2; ++mm)
#pragma unroll
                for (int ks = 0; ks < 2; ++ks)
                    af[mm][ks] = *(const s16x8*)&As[16384 + (wm + (2 * q + mm) * 16 + c) * 64 +
                                                    (((ks * 4 + qd) ^ (c & 7)) * 8)];
            if (q == 0) {
                if (ktA + 2 < 16) stageA(ktA + 2, 0, 0);
            } else if (q == 1) {
                if (ktA + 2 < 16) stageA(ktA + 2, 1, 0);
            } else if (q == 2) {
                if (ktB + 2 < 16) stageB(ktB + 2, 0, 1);
            } else {
                if (ktB + 2 < 16) stageB(ktB + 2, 1, 1);
            }
            __builtin_amdgcn_s_barrier();
            asm volatile("s_waitcnt lgkmcnt(0)" ::: "memory");
            __builtin_amdgcn_sched_barrier(0);
            __builtin_amdgcn_s_setprio(1);
#pragma unroll
            for (int mm = 0; mm < 2; ++mm)
#pragma unroll
                for (int n = 0; n < 4; ++n)
#pragma unroll
                    for (int ks = 0; ks < 2; ++ks)
                        acc[2 * q + mm][n] =
                            mfma16(af[mm][ks], bf[n][ks], acc[2 * q + mm][n]);
            __builtin_amdgcn_s_setprio(0);
            if (q == 3 && it < 7)   // publish next slot0
                asm volatile("s_waitcnt vmcnt(4)" ::: "memory");
            __builtin_amdgcn_s_barrier();
        }
    }

    // epilogue
#pragma unroll
    for (int m = 0; m < 8; ++m)
#pragma unroll
        for (int n = 0; n < 4; ++n) {
            const int colg = n0 + wn + n * 16 + c;
#pragma unroll
            for (int r = 0; r < 4; ++r) {
                const int rowg = m0 + wm + m * 16 + qd * 4 + r;
                if (EPI == 0) {
                    outp[(size_t)rowg * Nout + colg] = f2b(acc[m][n][r] + bv[n]);
                } else if (EPI == 2) {
                    outp[(size_t)rowg * Nout + colg] =
                        f2b(gelu_fast(acc[m][n][r] + bv[n]));
                } else {
                    pout[(size_t)rowg * 1024 + colg] = acc[m][n][r];
                }
            }
        }
}

// =====================================================================
// Split-K GEMM, 128x128, BK=64 (used for O-proj only).
// =====================================================================
__global__ __launch_bounds__(256) void gemm_splitk(const u16* __restrict__ A,
                                                   const u16* __restrict__ Bt,
                                                   Ptr4 parts,
                                                   int N, int Ktot, int Kc) {
    __shared__ __align__(16) u16 As[128 * 64];
    __shared__ __align__(16) u16 Bs[128 * 64];
    const int t = threadIdx.x, lane = t & 63;
    const int w = t >> 6, wm = (w >> 1) * 64, wn = (w & 1) * 64;
    const int c = lane & 15, qd = lane >> 4;
    const int n0 = blockIdx.x * 128, m0 = blockIdx.y * 128;
    const int z = blockIdx.z;
    float* out = parts.p[z];

    const int srow = t >> 3;
    const int sch8 = ((t & 7) ^ (srow & 7)) * 8;
    const u16* Ag = A + (size_t)(m0 + srow) * Ktot + z * Kc + sch8;
    const u16* Bg = Bt + (size_t)(n0 + srow) * Ktot + z * Kc + sch8;
    const size_t rstride = (size_t)32 * Ktot;

    f32x4 acc[4][4] = {};
    for (int kt = 0; kt < Kc; kt += 64) {
        __syncthreads();
#pragma unroll
        for (int g = 0; g < 4; g++) {
            gl_lds16(Ag + g * rstride, &As[t * 8 + g * 2048]);
            gl_lds16(Bg + g * rstride, &Bs[t * 8 + g * 2048]);
        }
        Ag += 64;
        Bg += 64;
        __syncthreads();
#pragma unroll
        for (int s = 0; s < 2; s++) {
            s16x8 a[4], b[4];
#pragma unroll
            for (int im = 0; im < 4; im++)
                a[im] = *(const s16x8*)&As[(wm + im * 16 + c) * 64 +
                                           (((s * 4 + qd) ^ (c & 7)) * 8)];
#pragma unroll
            for (int jn = 0; jn < 4; jn++)
                b[jn] = *(const s16x8*)&Bs[(wn + jn * 16 + c) * 64 +
                                           (((s * 4 + qd) ^ (c & 7)) * 8)];
#pragma unroll
            for (int im = 0; im < 4; im++)
#pragma unroll
                for (int jn = 0; jn < 4; jn++)
                    acc[im][jn] = mfma16(a[im], b[jn], acc[im][jn]);
        }
    }

#pragma unroll
    for (int im = 0; im < 4; im++)
#pragma unroll
        for (int jn = 0; jn < 4; jn++) {
            const int colg = n0 + wn + jn * 16 + c;
#pragma unroll
            for (int r = 0; r < 4; r++) {
                const int rowg = m0 + wm + im * 16 + qd * 4 + r;
                out[(size_t)rowg * N + colg] = acc[im][jn][r];
            }
        }
}

// =====================================================================
// Split-K reduce. One block per row (1024 cols, float4/thread).
// =====================================================================
template <int S, bool NORM>
__global__ __launch_bounds__(256) void reduce_kernel(Ptr4 parts,
                                                     const float* __restrict__ bias,
                                                     const float* __restrict__ resid,
                                                     const float* __restrict__ scale,
                                                     float* __restrict__ yout,
                                                     u16* __restrict__ xnout) {
    __shared__ float red[4];
    const int t = threadIdx.x, row = blockIdx.x;
    const size_t base = (size_t)row * 1024;
    float4 v = ((const float4*)(resid + base))[t];
    float4 bv = ((const float4*)bias)[t];
    v.x += bv.x; v.y += bv.y; v.z += bv.z; v.w += bv.w;
#pragma unroll
    for (int s = 0; s < S; s++) {
        float4 pv = ((const float4*)(parts.p[s] + base))[t];
        v.x += pv.x; v.y += pv.y; v.z += pv.z; v.w += pv.w;
    }
    ((float4*)(yout + base))[t] = v;
    if (NORM) {
        float ss = v.x * v.x + v.y * v.y + v.z * v.z + v.w * v.w;
#pragma unroll
        for (int off = 1; off < 64; off <<= 1) ss += __shfl_xor(ss, off);
        if ((t & 63) == 0) red[t >> 6] = ss;
        __syncthreads();
        float tot = red[0] + red[1] + red[2] + red[3];
        float inv = 1.f / (sqrtf(tot * (1.f / 1024.f)) + 1e-8f);
        float4 s = ((const float4*)scale)[t];
        u16x4 o;
        o[0] = f2b(v.x * inv * s.x);
        o[1] = f2b(v.y * inv * s.y);
        o[2] = f2b(v.z * inv * s.z);
        o[3] = f2b(v.w * inv * s.w);
        ((u16x4*)(xnout + base))[t] = o;
    }
}

// =====================================================================
// Flash attention v12: 2-tile fusion + K=32 PV (see R7 notes).
// =====================================================================
__global__ __launch_bounds__(256, 2) void attn_kernel(const u16* __restrict__ qkv,
                                                      const u16* __restrict__ vT,
                                                      u16* __restrict__ attn) {
    __shared__ __align__(16) char smem[65536];
    __shared__ float LS[4][64];
    u16* SM = (u16*)smem;

    const int t = threadIdx.x, lane = t & 63, w = t >> 6;
    const int c = lane & 15, g = lane >> 4;

    const int id = blockIdx.x;
    const int logical = (id & 7) * 128 + (id >> 3);
    const int bh = logical >> 5, qb = logical & 31;
    const int b = bh >> 4, h = bh & 15;
    const int q0 = qb * 64;
    const size_t rowbase = (size_t)b * 2048;

    const u16* kg = qkv + rowbase * 3072 + 1024 + h * 64;
    const u16* vg = vT + (size_t)bh * 64 * 2048;

    u16* WS = SM + w * 8192;

    const int kr = lane >> 3, ks8 = lane & 7;
    const int ksw = (ks8 ^ (kr & 7)) * 8;
    const int vr = lane >> 1, vh = (lane & 1) * 8;

    auto stage = [&](int it, int bi) {
        u16* B = WS + bi * 2048;
        const u16* kq = kg + (size_t)(it * 64 + w * 16) * 3072;
        const u16* vq = vg + it * 64 + w * 16;
        gl_lds16(kq + (size_t)kr * 3072 + ksw,       &B[lane * 8]);
        gl_lds16(kq + (size_t)(kr + 8) * 3072 + ksw, &B[512 + lane * 8]);
        gl_lds16(vq + (size_t)vr * 2048 + vh,        &B[1024 + lane * 8]);
        gl_lds16(vq + (size_t)(vr + 32) * 2048 + vh, &B[1536 + lane * 8]);
    };

    s16x8 qf[4][2];
    {
        const u16* qg = qkv + (rowbase + q0) * 3072 + h * 64;
#pragma unroll
        for (int jn = 0; jn < 4; jn++)
#pragma unroll
            for (int ks = 0; ks < 2; ks++)
                qf[jn][ks] = *(const s16x8*)&qg[(size_t)(jn * 16 + c) * 3072 +
                                                ks * 32 + g * 8];
    }

    stage(0, 0);
    stage(1, 1);
    stage(2, 2);
    stage(3, 3);

    f32x4 acc[4][4] = {};
    float ls[4] = {};

    for (int j = 0; j < 16; j++) {
        if (j < 15)
            asm volatile("s_waitcnt vmcnt(8)" ::: "memory");
        else
            asm volatile("s_waitcnt vmcnt(0)" ::: "memory");
        __builtin_amdgcn_sched_barrier(0);

        const u16* Kb0 = WS + ((2 * j) & 3) * 2048;
        const u16* Kb1 = WS + ((2 * j + 1) & 3) * 2048;
        const u16* Vb0 = Kb0 + 1024;
        const u16* Vb1 = Kb1 + 1024;

        s16x8 kf0[2], kf1[2];
#pragma unroll
        for (int ks = 0; ks < 2; ks++) {
            const int sw = ((ks * 4 + g) ^ (c & 7)) * 8;
            kf0[ks] = *(const s16x8*)&Kb0[c * 64 + sw];
            kf1[ks] = *(const s16x8*)&Kb1[c * 64 + sw];
        }
        s16x8 vf[4];
#pragma unroll
        for (int im = 0; im < 4; im++) {
            s16x4 v0 = *(const s16x4*)&Vb0[(im * 16 + c) * 16 + g * 4];
            s16x4 v1 = *(const s16x4*)&Vb1[(im * 16 + c) * 16 + g * 4];
            vf[im] = __builtin_shufflevector(v0, v1, 0, 1, 2, 3, 4, 5, 6, 7);
        }

        s16x8 pb[4];
        {
            f32x4 sc[4] = {};
            __builtin_amdgcn_s_setprio(1);
#pragma unroll
            for (int ks = 0; ks < 2; ks++)
#pragma unroll
                for (int jn = 0; jn < 4; jn++)
                    sc[jn] = mfma16(kf0[ks], qf[jn][ks], sc[jn]);
            __builtin_amdgcn_s_setprio(0);
#pragma unroll
            for (int jn = 0; jn < 4; jn++) {
                float p0 = exp2_fast(sc[jn][0]);
                float p1 = exp2_fast(sc[jn][1]);
                float p2 = exp2_fast(sc[jn][2]);
                float p3 = exp2_fast(sc[jn][3]);
                ls[jn] += (p0 + p1) + (p2 + p3);
                pb[jn][0] = f2b(p0); pb[jn][1] = f2b(p1);
                pb[jn][2] = f2b(p2); pb[jn][3] = f2b(p3);
            }
        }
        {
            f32x4 sc[4] = {};
            __builtin_amdgcn_s_setprio(1);
#pragma unroll
            for (int ks = 0; ks < 2; ks++)
#pragma unroll
                for (int jn = 0; jn < 4; jn++)
                    sc[jn] = mfma16(kf1[ks], qf[jn][ks], sc[jn]);
            __builtin_amdgcn_s_setprio(0);
#pragma unroll
            for (int jn = 0; jn < 4; jn++) {
                float p0 = exp2_fast(sc[jn][0]);
                float p1 = exp2_fast(sc[jn][1]);
                float p2 = exp2_fast(sc[jn][2]);
                float p3 = exp2_fast(sc[jn][3]);
                ls[jn] += (p0 + p1) + (p2 + p3);
                pb[jn][4] = f2b(p0); pb[jn][5] = f2b(p1);
                pb[jn][6] = f2b(p2); pb[jn][7] = f2b(p3);
            }
        }

        __builtin_amdgcn_s_setprio(1);
#pragma unroll
        for (int im = 0; im < 4; im++)
#pragma unroll
            for (int jn = 0; jn < 4; jn++)
                acc[im][jn] = mfma16(vf[im], pb[jn], acc[im][jn]);
        __builtin_amdgcn_s_setprio(0);

        __builtin_amdgcn_sched_barrier(0);
        if (j < 14) {
            stage(2 * j + 4, (2 * j) & 3);
            stage(2 * j + 5, (2 * j + 1) & 3);
        }
    }

#pragma unroll
    for (int jn = 0; jn < 4; jn++) {
        float v = ls[jn];
        v += __shfl_xor(v, 16);
        v += __shfl_xor(v, 32);
        ls[jn] = v;
    }
    if (lane < 16) {
#pragma unroll
        for (int jn = 0; jn < 4; jn++) LS[w][jn * 16 + lane] = ls[jn];
    }

    float* SC = (float*)smem;
#pragma unroll
    for (int src = 3; src >= 1; --src) {
        __syncthreads();
        if (w == src) {
#pragma unroll
            for (int im = 0; im < 4; im++)
#pragma unroll
                for (int jn = 0; jn < 4; jn++)
#pragma unroll
                    for (int r = 0; r < 4; r++)
                        SC[(im * 16 + g * 4 + r) * 66 + jn * 16 + c] =
                            acc[im][jn][r];
        }
        __syncthreads();
        if (w == src - 1) {
#pragma unroll
            for (int im = 0; im < 4; im++)
#pragma unroll
                for (int jn = 0; jn < 4; jn++)
#pragma unroll
                    for (int r = 0; r < 4; r++)
                        acc[im][jn][r] +=
                            SC[(im * 16 + g * 4 + r) * 66 + jn * 16 + c];
        }
    }
    __syncthreads();

    u16* OT = (u16*)smem;
    if (w == 0) {
#pragma unroll
        for (int jn = 0; jn < 4; jn++) {
            const int q = jn * 16 + c;
            const float inv = 1.f / (LS[0][q] + LS[1][q] + LS[2][q] + LS[3][q]);
#pragma unroll
            for (int im = 0; im < 4; im++)
#pragma unroll
                for (int r = 0; r < 4; r++)
                    OT[q * 72 + im * 16 + g * 4 + r] = f2b(acc[im][jn][r] * inv);
        }
    }
    __syncthreads();

    {
        const int q = t >> 2, d0 = (t & 3) * 16;
        const int grow = b * 2048 + q0 + q;
        u16* dst = attn + (size_t)grow * 1024 + h * 64 + d0;
        *(s16x8*)dst = *(const s16x8*)&OT[q * 72 + d0];
        *((s16x8*)dst + 1) = *((const s16x8*)&OT[q * 72 + d0] + 1);
    }
}

// =====================================================================
extern "C" void kernel_launch(void* const* d_in, const int* in_sizes, int n_in,
                              void* d_out, int out_size, void* d_ws, size_t ws_size,
                              hipStream_t stream) {
    const float* x = (const float*)d_in[0];
    const float* wq = (const float*)d_in[1];
    const float* bq = (const float*)d_in[2];
    const float* wk = (const float*)d_in[3];
    const float* bk = (const float*)d_in[4];
    const float* wv = (const float*)d_in[5];
    const float* bv = (const float*)d_in[6];
    const float* wo = (const float*)d_in[7];
    const float* bo = (const float*)d_in[8];
    const float* scale1 = (const float*)d_in[9];
    const float* scale2 = (const float*)d_in[10];
    const float* w1 = (const float*)d_in[11];
    const float* b1 = (const float*)d_in[12];
    const float* w2 = (const float*)d_in[13];
    const float* b2 = (const float*)d_in[14];
    float* out = (float*)d_out;

    char* ws = (char*)d_ws;
    size_t off = 0;
    auto alloc = [&](size_t bytes) -> char* {
        char* p = ws + off;
        off += (bytes + 255) & ~(size_t)255;
        return p;
    };
    u16* wqkvT = (u16*)alloc((size_t)3072 * 1024 * 2);   //  6 MB  [ws+0]
    u16* woT   = (u16*)alloc((size_t)1024 * 1024 * 2);   //  2 MB
    u16* w1T   = (u16*)alloc((size_t)4096 * 1024 * 2);   //  8 MB
    u16* w2T   = (u16*)alloc((size_t)1024 * 4096 * 2);   //  8 MB
    float* bqkv = (float*)alloc(3072 * 4);
    u16* xn    = (u16*)alloc((size_t)4096 * 1024 * 2);   //  8 MB
    u16* qkv   = (u16*)alloc((size_t)4096 * 3072 * 2);   // 24 MB
    u16* vT    = (u16*)alloc((size_t)32 * 64 * 2048 * 2);//  8 MB
    u16* attnb = (u16*)alloc((size_t)4096 * 1024 * 2);   //  8 MB
    float* y1  = (float*)alloc((size_t)4096 * 1024 * 4); // 16 MB
    u16* hbuf  = (u16*)alloc((size_t)4096 * 4096 * 2);   // 32 MB

    const size_t SPLIT = (size_t)4096 * 1024;
    Ptr4 po; po.p[0] = (float*)qkv; po.p[1] = (float*)qkv + SPLIT;
    po.p[2] = nullptr; po.p[3] = nullptr;
    Ptr4 pf; pf.p[0] = (float*)xn; pf.p[1] = (float*)xn + SPLIT;
    pf.p[2] = (float*)xn + 2 * SPLIT; pf.p[3] = (float*)wqkvT;
    Ptr4 pz = {};

    dim3 blk(256);

    TW6 tw;
    tw.w[0] = wq; tw.o[0] = wqkvT;                          tw.mode[0] = 1;
    tw.w[1] = wk; tw.o[1] = wqkvT + (size_t)1024 * 1024;    tw.mode[1] = 2;
    tw.w[2] = wv; tw.o[2] = wqkvT + (size_t)2048 * 1024;    tw.mode[2] = 0;
    tw.w[3] = wo; tw.o[3] = woT;                            tw.mode[3] = 0;
    tw.w[4] = w1; tw.o[4] = w1T;                            tw.mode[4] = 0;
    tw.w[5] = w2; tw.o[5] = w2T;                            tw.mode[5] = 0;
    tw.bq = bq; tw.bk = bk; tw.bv = bv; tw.bqkv = bqkv;
    prep_weights<<<dim3(128, 32, 6), blk, 0, stream>>>(tw);

    // 1. RMSNorm1
    rmsnorm_kernel<<<4096, blk, 0, stream>>>(x, scale1, xn);
    // 2. QKV GEMM via 256^2 8-phase (rotary + log2e pre-folded) -> qkv bf16
    gemm256<0><<<dim3(192), dim3(512), 0, stream>>>(xn, wqkvT, bqkv, pz, qkv, 3072, 12, 24, 1024);
    // 3. per-head V transpose
    transpose_v<<<dim3(64, 2, 32), blk, 0, stream>>>(qkv, vT);
    // 4. flash attention v12 (2-tile fusion, K=32 PV, wave-private staging)
    attn_kernel<<<dim3(1024), blk, 0, stream>>>(qkv, vT, attnb);
    // 5. O-proj split-K=2
    gemm_splitk<<<dim3(8, 32, 2), blk, 0, stream>>>(attnb, woT, po, 1024, 1024, 512);
    // 6. reduce + bias + resid + RMSNorm2 -> y1 fp32, xn bf16
    reduce_kernel<2, true><<<4096, blk, 0, stream>>>(po, bo, x, scale2, y1, xn);
    // 7. FFN1 + fast exact GELU via 256^2 8-phase -> hbuf bf16
    gemm256<2><<<dim3(256), dim3(512), 0, stream>>>(xn, w1T, b1, pz, hbuf, 4096, 16, 32, 1024);
    // 8. FFN2 via 256^2 8-phase split-K=4 -> fp32 partials
    gemm256<3><<<dim3(64, 4), dim3(512), 0, stream>>>(hbuf, w2T, nullptr, pf, nullptr, 1024, 4, 8, 4096);
    // 9. reduce + bias + resid -> out fp32
    reduce_kernel<4, false><<<4096, blk, 0, stream>>>(pf, b2, y1, nullptr, out, nullptr);
}